// Round 11
// baseline (3242.928 us; speedup 1.0000x reference)
//
#include <hip/hip_runtime.h>

#define BB 512
#define TT 256
#define FDIM 128
#define HDIM 512
#define FFD 1024
#define OUTD 64
#define PADV -999.0f
#define NBLK 256
#define NTHR 512
#define PGRP (4 * 64 * 16)        // pscr floats per (group): 4 ocol x 64 rows x 16 cols
#define PSLOT (8 * PGRP)          // pscr floats per ping-pong slot (8 groups)

typedef __bf16 bf16_t;
typedef bf16_t bf16x8 __attribute__((ext_vector_type(8)));
typedef float f32x4 __attribute__((ext_vector_type(4)));
typedef unsigned int u32;
typedef u32 u32x4 __attribute__((ext_vector_type(4)));
typedef unsigned long long u64;

// R18 LDS layout: DWORD-PLANE fragments (bank-conflict-free; verified:
// SQ_LDS_BANK_CONFLICT 6.15e8 -> 1.05e7). dword d of lane l at dword index
// frag*256 + d*64 + l. R20 hprev: own h-slice stash in LDS.
union LdsU {
  struct {                        // A-role (GRU gates), 128 blocks
    u32 rzf[80 * 256];            // [j<4][ks<20: 0..3 x-part, 4..19 h-part]
    u32 nhf[32 * 256];            // [j2<2][ks<16] h_n (Whh rows 1024+)
    u32 nif[8 * 256];             // [j2<2][ks<4]  i_n (Wih rows 1024+)
    float  ex[4][64][33];         // gate exchange [r,z,nh,ni][row][col]
    u64 hprev[64][8];             // own (b0-rows x c0-cols) h slice
  } a;
  struct {                        // B-role (FF1 + FF2-chunk), 128 blocks
    u32 w1f[64 * 256];            // [j<4][ks<16]
    u32 w2f[8 * 256];             // [ks<8] own K-quarter of W2
    bf16_t st[64 * 72];           // FF1 output restage
  } b;
};

__device__ __forceinline__ f32x4 mfma16(bf16x8 a, bf16x8 b, f32x4 c) {
  return __builtin_amdgcn_mfma_f32_16x16x32_bf16(a, b, c, 0, 0, 0);
}
__device__ __forceinline__ float sigm(float x) { return 1.f / (1.f + __expf(-x)); }
__device__ __forceinline__ float tanh_f(float x) { return 2.f / (1.f + __expf(-2.f * x)) - 1.f; }

// R20 flag barrier: per-sibling monotone flag STORES + 32-lane parallel
// poll (wave 0 only): lanes 0-15 spin on f1[lane] >= v1, 16-31 on f2 >= v2.
__device__ __forceinline__ void wait_flags(unsigned* f1, unsigned v1,
                                           unsigned* f2, unsigned v2) {
  const int l = threadIdx.x & 63;
  if (l < 32) {
    unsigned* p = (l < 16) ? (f1 + l) : (f2 + (l - 16));
    const unsigned v = (l < 16) ? v1 : v2;
    while (__hip_atomic_load(p, __ATOMIC_RELAXED, __HIP_MEMORY_SCOPE_AGENT) < v)
      __builtin_amdgcn_s_sleep(1);
  }
}

// LESSONS (stub-failure = silent compile fail -> harness fallback):
//  1. __hip_atomic_* pointer args must be NON-CONST, used inline.
//  2. NO prefetch arrays >= 64 VGPRs feeding unrolled MFMA loops.
//  3. R12: inline-asm cache-flag loads -> stub fallback.
//  4. R12/13/14: load batching via asm / u64[16] arrays / MACROs -> stub.
//     Proven: named u64 q[2] pairs, adjacent loads INLINE (R16/R19/R20).
//  5. R16: wave K-split + NEW cross-wave reduction = 2.4x regression.
//  6. R17/R19 (load-group depth), R20 (flag barrier + epilogue hoist +
//     hprev): all ~null. R18 (bank-conflict fix): real -18%.
//  7. Occupancy was 1 wave/SIMD (11.9%) -> every issue/latency cycle
//     exposed. R21: 512-thread blocks, wave-PAIRS split the j-fragments
//     (disjoint ex slots / st cols; FF2 K-halves sum via the EXISTING
//     pscr atomicAdd -> no new reduction machinery, unlike R16).
//
// Sync graph (unchanged): flagA[g][sib] = t+2 after A iter t (1 after
// zero). flagB[g][fc] = u+1 after B iter u. A(t) waits flagA>=t+1 &
// (t>=2) flagB>=t-1. B(u) waits flagB>=u & (u<TT) flagA>=u+2.

__global__ __launch_bounds__(NTHR) void gru_net_kernel(
    const float* __restrict__ x, const int* __restrict__ seq,
    const float* __restrict__ Wih, const float* __restrict__ Whh,
    const float* __restrict__ bih, const float* __restrict__ bhh,
    const float* __restrict__ W1, const float* __restrict__ b1,
    const float* __restrict__ W2, const float* __restrict__ b2,
    float* __restrict__ out,
    bf16_t* __restrict__ hb, bf16_t* __restrict__ ff, bf16_t* __restrict__ hd,
    float* __restrict__ psc, unsigned* __restrict__ bar) {
  __shared__ LdsU L;
  __shared__ float biasA[4][32];
  __shared__ float b1s[64];
  __shared__ float b2s[16];
  __shared__ int   seqA[64];
  __shared__ int   seqC[64];

  const int blk = blockIdx.x, tid = threadIdx.x;
  const int wv = tid >> 6, lane = tid & 63;
  const int wrow = wv & 3, whalf = wv >> 2;   // 16-row tile, fragment half
  const int q = lane >> 4, col16 = lane & 15, q8 = q * 8;
  const bool isA = blk < 128;

  const int grp = isA ? (blk & 7) : ((blk - 128) & 7);
  unsigned* flagA = bar + grp * 32;           // 16 u32 in a 128B line
  unsigned* flagB = bar + (8 + grp) * 32;

  int b0 = 0, c0 = 0, f0 = 0;
  if (isA) {
    const int sib = blk >> 3;      // sibling index 0..15 (h-col group)
    b0 = (blk & 7) * 64;           // batch row group (8)
    c0 = sib * 32;                 // h-col group (16)
    // rzf: frag fi=j*20+ks; lane(q,c) elem e = W[grow(j*16+c)][k], where
    // ks<4 -> Wih k=ks*32+q*8+e ; ks>=4 -> Whh k=(ks-4)*32+q*8+e
    for (int i = tid; i < 80 * 64; i += NTHR) {
      const int ln = i & 63, fi = i >> 6;
      const int j = fi / 20, ks = fi - j * 20;
      const int cc = ln & 15, qq = ln >> 4;
      const int colj = j * 16 + cc;
      const int grow = (colj < 32) ? (c0 + colj) : (512 + c0 + (colj - 32));
      bf16_t tmp[8];
      if (ks < 4) {
        const float* src = Wih + (size_t)grow * FDIM + ks * 32 + qq * 8;
        for (int e = 0; e < 8; ++e) tmp[e] = (bf16_t)src[e];
      } else {
        const float* src = Whh + (size_t)grow * HDIM + (ks - 4) * 32 + qq * 8;
        for (int e = 0; e < 8; ++e) tmp[e] = (bf16_t)src[e];
      }
      const u32* t32 = (const u32*)tmp;
      u32* dst = &L.a.rzf[fi * 256 + ln];
      dst[0] = t32[0]; dst[64] = t32[1]; dst[128] = t32[2]; dst[192] = t32[3];
    }
    for (int i = tid; i < 32 * 64; i += NTHR) {   // nhf: fi=j2*16+ks
      const int ln = i & 63, fi = i >> 6;
      const int j2 = fi >> 4, ks = fi & 15;
      const int cc = ln & 15, qq = ln >> 4;
      const int grow = 1024 + c0 + j2 * 16 + cc;
      const float* src = Whh + (size_t)grow * HDIM + ks * 32 + qq * 8;
      bf16_t tmp[8];
      for (int e = 0; e < 8; ++e) tmp[e] = (bf16_t)src[e];
      const u32* t32 = (const u32*)tmp;
      u32* dst = &L.a.nhf[fi * 256 + ln];
      dst[0] = t32[0]; dst[64] = t32[1]; dst[128] = t32[2]; dst[192] = t32[3];
    }
    for (int i = tid; i < 8 * 64; i += NTHR) {    // nif: fi=j2*4+ks
      const int ln = i & 63, fi = i >> 6;
      const int j2 = fi >> 2, ks = fi & 3;
      const int cc = ln & 15, qq = ln >> 4;
      const int grow = 1024 + c0 + j2 * 16 + cc;
      const float* src = Wih + (size_t)grow * FDIM + ks * 32 + qq * 8;
      bf16_t tmp[8];
      for (int e = 0; e < 8; ++e) tmp[e] = (bf16_t)src[e];
      const u32* t32 = (const u32*)tmp;
      u32* dst = &L.a.nif[fi * 256 + ln];
      dst[0] = t32[0]; dst[64] = t32[1]; dst[128] = t32[2]; dst[192] = t32[3];
    }
    if (tid < 32) {
      biasA[0][tid] = bih[c0 + tid] + bhh[c0 + tid];
      biasA[1][tid] = bih[512 + c0 + tid] + bhh[512 + c0 + tid];
      biasA[2][tid] = bih[1024 + c0 + tid];   // i_n bias
      biasA[3][tid] = bhh[1024 + c0 + tid];   // h_n bias
    }
    if (tid < 64) seqA[tid] = seq[b0 + tid];

    // zero OWN shard of h_{-1} (slot 1) + LDS hprev: 64 rows x 32 cols
    for (int i = tid; i < 512; i += NTHR) {
      const int r = i >> 3, cq = (i & 7) * 4;
      __hip_atomic_store((u64*)(hb + (size_t)BB * HDIM + (size_t)(b0 + r) * HDIM + c0 + cq),
                         0ull, __ATOMIC_RELAXED, __HIP_MEMORY_SCOPE_AGENT);
      ((u64*)L.a.hprev)[i] = 0ull;
    }
    __syncthreads();                         // drain zero stores + LDS staging
    if (tid == 0)
      __hip_atomic_store(&flagA[sib], 1u, __ATOMIC_RELAXED, __HIP_MEMORY_SCOPE_AGENT);

    // j-fragment assignment for this wave: rz j0,j1 ; nh/ni jn
    const int j0 = whalf * 2, j1 = whalf * 2 + 1, jn = whalf;

    // ---- A loop: one GRU timestep per iteration, group-local sync ----
    for (int t = 0; t < TT; ++t) {
      // --- pre-barrier: x-part (depends on t only; overlaps sibling wait) ---
      const int rA = b0 + wrow * 16 + col16;
      const float* paxf = x + ((size_t)rA * TT + t) * FDIM;
      const f32x4 zz = {0.f, 0.f, 0.f, 0.f};
      f32x4 acc0 = zz, acc1 = zz;   // rz j0, j1
      f32x4 accn = zz;              // nh jn
      f32x4 acci = zz;              // ni jn
      #pragma unroll
      for (int ks = 0; ks < 4; ++ks) {
        const int ko = ks * 32 + q8;
        const float4 u0 = *(const float4*)(paxf + ko);
        const float4 u1 = *(const float4*)(paxf + ko + 4);
        bf16x8 av;
        av[0]=(bf16_t)u0.x; av[1]=(bf16_t)u0.y; av[2]=(bf16_t)u0.z; av[3]=(bf16_t)u0.w;
        av[4]=(bf16_t)u1.x; av[5]=(bf16_t)u1.y; av[6]=(bf16_t)u1.z; av[7]=(bf16_t)u1.w;
        {
          const u32* pz = &L.a.rzf[(size_t)(j0 * 20 + ks) * 256 + lane];
          const u32x4 tz = {pz[0], pz[64], pz[128], pz[192]};
          acc0 = mfma16(av, *(const bf16x8*)&tz, acc0);
        }
        {
          const u32* pz = &L.a.rzf[(size_t)(j1 * 20 + ks) * 256 + lane];
          const u32x4 tz = {pz[0], pz[64], pz[128], pz[192]};
          acc1 = mfma16(av, *(const bf16x8*)&tz, acc1);
        }
        {
          const u32* pn = &L.a.nif[(size_t)(jn * 4 + ks) * 256 + lane];
          const u32x4 tn = {pn[0], pn[64], pn[128], pn[192]};
          acci = mfma16(av, *(const bf16x8*)&tn, acci);
        }
      }
      // --- barrier: siblings done t-1 AND B done t-2 (one parallel poll) ---
      if (wv == 0)
        wait_flags(flagA, (unsigned)(t + 1), flagB, (t >= 2) ? (unsigned)(t - 1) : 0u);
      __syncthreads();

      bf16_t* hr = hb + (size_t)((t + 1) & 1) * BB * HDIM;
      bf16_t* hw = hb + (size_t)(t & 1) * BB * HDIM;
      bf16_t* fw = ff + (size_t)(t & 1) * BB * HDIM;
      bf16_t* pah = hr + (size_t)rA * HDIM;
      // h part: 16 ks in QUADS (4 named pairs, 8 adjacent loads per group)
      #pragma unroll
      for (int kp = 0; kp < 4; ++kp) {
        const int ks0 = kp * 4, ks1 = kp * 4 + 1, ks2 = kp * 4 + 2, ks3 = kp * 4 + 3;
        const int ko0 = ks0 * 32 + q8, ko1 = ks1 * 32 + q8;
        const int ko2 = ks2 * 32 + q8, ko3 = ks3 * 32 + q8;
        u64 hqa[2];
        u64 hqb[2];
        u64 hqc[2];
        u64 hqd[2];
        hqa[0] = __hip_atomic_load((u64*)(pah + ko0),     __ATOMIC_RELAXED, __HIP_MEMORY_SCOPE_AGENT);
        hqa[1] = __hip_atomic_load((u64*)(pah + ko0) + 1, __ATOMIC_RELAXED, __HIP_MEMORY_SCOPE_AGENT);
        hqb[0] = __hip_atomic_load((u64*)(pah + ko1),     __ATOMIC_RELAXED, __HIP_MEMORY_SCOPE_AGENT);
        hqb[1] = __hip_atomic_load((u64*)(pah + ko1) + 1, __ATOMIC_RELAXED, __HIP_MEMORY_SCOPE_AGENT);
        hqc[0] = __hip_atomic_load((u64*)(pah + ko2),     __ATOMIC_RELAXED, __HIP_MEMORY_SCOPE_AGENT);
        hqc[1] = __hip_atomic_load((u64*)(pah + ko2) + 1, __ATOMIC_RELAXED, __HIP_MEMORY_SCOPE_AGENT);
        hqd[0] = __hip_atomic_load((u64*)(pah + ko3),     __ATOMIC_RELAXED, __HIP_MEMORY_SCOPE_AGENT);
        hqd[1] = __hip_atomic_load((u64*)(pah + ko3) + 1, __ATOMIC_RELAXED, __HIP_MEMORY_SCOPE_AGENT);
        const bf16x8 av0 = *(const bf16x8*)hqa;
        const bf16x8 av1 = *(const bf16x8*)hqb;
        const bf16x8 av2 = *(const bf16x8*)hqc;
        const bf16x8 av3 = *(const bf16x8*)hqd;
        {
          const u32* pz = &L.a.rzf[(size_t)(j0 * 20 + 4 + ks0) * 256 + lane];
          const u32x4 tz = {pz[0], pz[64], pz[128], pz[192]};
          acc0 = mfma16(av0, *(const bf16x8*)&tz, acc0);
        }
        {
          const u32* pz = &L.a.rzf[(size_t)(j1 * 20 + 4 + ks0) * 256 + lane];
          const u32x4 tz = {pz[0], pz[64], pz[128], pz[192]};
          acc1 = mfma16(av0, *(const bf16x8*)&tz, acc1);
        }
        {
          const u32* pn = &L.a.nhf[(size_t)(jn * 16 + ks0) * 256 + lane];
          const u32x4 tn = {pn[0], pn[64], pn[128], pn[192]};
          accn = mfma16(av0, *(const bf16x8*)&tn, accn);
        }
        {
          const u32* pz = &L.a.rzf[(size_t)(j0 * 20 + 4 + ks1) * 256 + lane];
          const u32x4 tz = {pz[0], pz[64], pz[128], pz[192]};
          acc0 = mfma16(av1, *(const bf16x8*)&tz, acc0);
        }
        {
          const u32* pz = &L.a.rzf[(size_t)(j1 * 20 + 4 + ks1) * 256 + lane];
          const u32x4 tz = {pz[0], pz[64], pz[128], pz[192]};
          acc1 = mfma16(av1, *(const bf16x8*)&tz, acc1);
        }
        {
          const u32* pn = &L.a.nhf[(size_t)(jn * 16 + ks1) * 256 + lane];
          const u32x4 tn = {pn[0], pn[64], pn[128], pn[192]};
          accn = mfma16(av1, *(const bf16x8*)&tn, accn);
        }
        {
          const u32* pz = &L.a.rzf[(size_t)(j0 * 20 + 4 + ks2) * 256 + lane];
          const u32x4 tz = {pz[0], pz[64], pz[128], pz[192]};
          acc0 = mfma16(av2, *(const bf16x8*)&tz, acc0);
        }
        {
          const u32* pz = &L.a.rzf[(size_t)(j1 * 20 + 4 + ks2) * 256 + lane];
          const u32x4 tz = {pz[0], pz[64], pz[128], pz[192]};
          acc1 = mfma16(av2, *(const bf16x8*)&tz, acc1);
        }
        {
          const u32* pn = &L.a.nhf[(size_t)(jn * 16 + ks2) * 256 + lane];
          const u32x4 tn = {pn[0], pn[64], pn[128], pn[192]};
          accn = mfma16(av2, *(const bf16x8*)&tn, accn);
        }
        {
          const u32* pz = &L.a.rzf[(size_t)(j0 * 20 + 4 + ks3) * 256 + lane];
          const u32x4 tz = {pz[0], pz[64], pz[128], pz[192]};
          acc0 = mfma16(av3, *(const bf16x8*)&tz, acc0);
        }
        {
          const u32* pz = &L.a.rzf[(size_t)(j1 * 20 + 4 + ks3) * 256 + lane];
          const u32x4 tz = {pz[0], pz[64], pz[128], pz[192]};
          acc1 = mfma16(av3, *(const bf16x8*)&tz, acc1);
        }
        {
          const u32* pn = &L.a.nhf[(size_t)(jn * 16 + ks3) * 256 + lane];
          const u32x4 tn = {pn[0], pn[64], pn[128], pn[192]};
          accn = mfma16(av3, *(const bf16x8*)&tn, accn);
        }
      }
      // dump gate sums to LDS exchange (C/D: col=lane&15, row=q*4+reg)
      // pair-waves write DISJOINT slots: whalf=0 -> sl0 + lo halves of
      // sl2/sl3; whalf=1 -> sl1 + hi halves.
      {
        const int rb = wrow * 16 + q * 4;
        #pragma unroll
        for (int rg = 0; rg < 4; ++rg) {
          L.a.ex[whalf][rb + rg][col16]      = acc0[rg];
          L.a.ex[whalf][rb + rg][16 + col16] = acc1[rg];
          L.a.ex[2][rb + rg][jn * 16 + col16] = accn[rg];
          L.a.ex[3][rb + rg][jn * 16 + col16] = acci[rg];
        }
      }
      __syncthreads();
      // elementwise GRU update: h_prev from LDS stash (no global RT)
      for (int e = tid; e < 512; e += NTHR) {
        const int row = e >> 3, cq = (e & 7) << 2;
        const int bidx = b0 + row;
        const u64 hp8 = L.a.hprev[row][cq >> 2];
        const bf16_t* hp4 = (const bf16_t*)&hp8;
        bf16_t hw4[4], fw4[4];
        const bool v = (t < seqA[row]);
        #pragma unroll
        for (int j = 0; j < 4; ++j) {
          const int c = cq + j;
          const float gr  = L.a.ex[0][row][c] + biasA[0][c];
          const float gz  = L.a.ex[1][row][c] + biasA[1][c];
          const float gnh = L.a.ex[2][row][c] + biasA[3][c];
          const float gni = L.a.ex[3][row][c] + biasA[2][c];
          const float r = sigm(gr), zg = sigm(gz);
          const float n = tanh_f(gni + r * gnh);
          const float hp = (float)hp4[j];
          const float hnew = (1.f - zg) * n + zg * hp;
          hw4[j] = (bf16_t)(v ? hnew : hp);
          fw4[j] = (bf16_t)(v ? hnew : 0.f);
        }
        L.a.hprev[row][cq >> 2] = *(u64*)hw4;
        __hip_atomic_store((u64*)(hw + (size_t)bidx * HDIM + c0 + cq), *(u64*)hw4,
                           __ATOMIC_RELAXED, __HIP_MEMORY_SCOPE_AGENT);
        __hip_atomic_store((u64*)(fw + (size_t)bidx * HDIM + c0 + cq), *(u64*)fw4,
                           __ATOMIC_RELAXED, __HIP_MEMORY_SCOPE_AGENT);
      }
      __syncthreads();                       // drain h/ff stores
      if (tid == 0)
        __hip_atomic_store(&flagA[sib], (unsigned)(t + 2), __ATOMIC_RELAXED, __HIP_MEMORY_SCOPE_AGENT);
    }
  } else {
    const int cidx = blk - 128;
    const int fc = cidx >> 3;      // 0..15 (sibling index)
    const int oc = fc & 3;         // out-col group (4 x 16 cols)
    const int kq = fc >> 2;        // K-quarter (4 x 256)
    const bool isFin = (fc < 4);   // finalizer blocks (one per (g, oc))
    b0 = (cidx & 7) * 64;          // batch group (same XCD residue as A)
    f0 = fc * 64;                  // FF col group (16)
    const int o0 = oc * 16;
    for (int i = tid; i < 64 * 64; i += NTHR) {   // w1f: fi=j*16+ks
      const int ln = i & 63, fi = i >> 6;
      const int j = fi >> 4, ks = fi & 15;
      const int cc = ln & 15, qq = ln >> 4;
      const int fcol = f0 + j * 16 + cc;
      const int kb = ks * 32 + qq * 8;
      bf16_t tmp[8];
      for (int e = 0; e < 8; ++e) tmp[e] = (bf16_t)W1[(size_t)(kb + e) * FFD + fcol];
      const u32* t32 = (const u32*)tmp;
      u32* dst = &L.b.w1f[fi * 256 + ln];
      dst[0] = t32[0]; dst[64] = t32[1]; dst[128] = t32[2]; dst[192] = t32[3];
    }
    if (tid < 64) b1s[tid] = b1[f0 + tid];
    for (int i = tid; i < 8 * 64; i += NTHR) {    // w2f: own K-quarter, fi=ks<8
      const int ln = i & 63, ks = i >> 6;
      const int cc = ln & 15, qq = ln >> 4;
      const int kb = kq * 256 + ks * 32 + qq * 8;
      bf16_t tmp[8];
      for (int e = 0; e < 8; ++e) tmp[e] = (bf16_t)W2[(kb + e) * OUTD + o0 + cc];
      const u32* t32 = (const u32*)tmp;
      u32* dst = &L.b.w2f[ks * 256 + ln];
      dst[0] = t32[0]; dst[64] = t32[1]; dst[128] = t32[2]; dst[192] = t32[3];
    }
    if (isFin) {
      if (tid < 16) b2s[tid] = b2[o0 + tid];
      if (tid < 64) seqC[tid] = seq[b0 + tid];
    }
    __syncthreads();               // LDS staging visible block-wide

    const int j0 = whalf * 2, j1 = whalf * 2 + 1;   // FF1 j split

    // ---- B loop: iter u = FF1(t=u), FF2-chunk adds(t=u-1), finalize(t=u-2)
    float* pg = psc + (size_t)grp * PGRP + (size_t)oc * (64 * 16);
    for (int u = 0; u <= TT + 1; ++u) {
      if (wv == 0)
        wait_flags(flagB, (unsigned)u, flagA, (u < TT) ? (unsigned)(u + 2) : 0u);
      __syncthreads();

      // --- hoisted issue: FF2 fragment loads (t=u-1; K-half per wave-pair)
      const int rCF = b0 + wrow * 16 + col16;
      bf16_t* paF = hd + (size_t)((u - 1) & 1) * BB * FFD + (size_t)rCF * FFD
                    + kq * 256 + whalf * 128 + q8;
      u64 fz0a = 0, fz0b = 0, fz1a = 0, fz1b = 0;
      u64 fz2a = 0, fz2b = 0, fz3a = 0, fz3b = 0;
      if (u >= 1 && u <= TT) {
        fz0a = __hip_atomic_load((u64*)(paF + 0 * 32),     __ATOMIC_RELAXED, __HIP_MEMORY_SCOPE_AGENT);
        fz0b = __hip_atomic_load((u64*)(paF + 0 * 32) + 1, __ATOMIC_RELAXED, __HIP_MEMORY_SCOPE_AGENT);
        fz1a = __hip_atomic_load((u64*)(paF + 1 * 32),     __ATOMIC_RELAXED, __HIP_MEMORY_SCOPE_AGENT);
        fz1b = __hip_atomic_load((u64*)(paF + 1 * 32) + 1, __ATOMIC_RELAXED, __HIP_MEMORY_SCOPE_AGENT);
        fz2a = __hip_atomic_load((u64*)(paF + 2 * 32),     __ATOMIC_RELAXED, __HIP_MEMORY_SCOPE_AGENT);
        fz2b = __hip_atomic_load((u64*)(paF + 2 * 32) + 1, __ATOMIC_RELAXED, __HIP_MEMORY_SCOPE_AGENT);
        fz3a = __hip_atomic_load((u64*)(paF + 3 * 32),     __ATOMIC_RELAXED, __HIP_MEMORY_SCOPE_AGENT);
        fz3b = __hip_atomic_load((u64*)(paF + 3 * 32) + 1, __ATOMIC_RELAXED, __HIP_MEMORY_SCOPE_AGENT);
      }
      // --- hoisted issue: finalize pscr loads (t2=u-2; tid<256 only)
      float* ppF = pg + (size_t)((u - 2) & 1) * PSLOT + (tid >> 2) * 16 + (tid & 3) * 4;
      u64 fp0 = 0, fp1 = 0;
      if (isFin && u >= 2 && tid < 256) {
        fp0 = __hip_atomic_load((u64*)ppF,     __ATOMIC_RELAXED, __HIP_MEMORY_SCOPE_AGENT);
        fp1 = __hip_atomic_load((u64*)ppF + 1, __ATOMIC_RELAXED, __HIP_MEMORY_SCOPE_AGENT);
      }

      if (u < TT) {                        // FF1 for t = u; j-pair split
        const int t = u;
        bf16_t* fr = ff + (size_t)(t & 1) * BB * HDIM;
        bf16_t* hwid = hd + (size_t)(t & 1) * BB * FFD;
        const int rB = b0 + wrow * 16 + col16;
        bf16_t* pa = fr + (size_t)rB * HDIM;
        const f32x4 zz = {0.f, 0.f, 0.f, 0.f};
        f32x4 acc0 = zz, acc1 = zz;
        #pragma unroll
        for (int kp = 0; kp < 4; ++kp) {
          const int ks0 = kp * 4, ks1 = kp * 4 + 1, ks2 = kp * 4 + 2, ks3 = kp * 4 + 3;
          const int ko0 = ks0 * 32 + q8, ko1 = ks1 * 32 + q8;
          const int ko2 = ks2 * 32 + q8, ko3 = ks3 * 32 + q8;
          u64 fqa[2];
          u64 fqb[2];
          u64 fqc[2];
          u64 fqd[2];
          fqa[0] = __hip_atomic_load((u64*)(pa + ko0),     __ATOMIC_RELAXED, __HIP_MEMORY_SCOPE_AGENT);
          fqa[1] = __hip_atomic_load((u64*)(pa + ko0) + 1, __ATOMIC_RELAXED, __HIP_MEMORY_SCOPE_AGENT);
          fqb[0] = __hip_atomic_load((u64*)(pa + ko1),     __ATOMIC_RELAXED, __HIP_MEMORY_SCOPE_AGENT);
          fqb[1] = __hip_atomic_load((u64*)(pa + ko1) + 1, __ATOMIC_RELAXED, __HIP_MEMORY_SCOPE_AGENT);
          fqc[0] = __hip_atomic_load((u64*)(pa + ko2),     __ATOMIC_RELAXED, __HIP_MEMORY_SCOPE_AGENT);
          fqc[1] = __hip_atomic_load((u64*)(pa + ko2) + 1, __ATOMIC_RELAXED, __HIP_MEMORY_SCOPE_AGENT);
          fqd[0] = __hip_atomic_load((u64*)(pa + ko3),     __ATOMIC_RELAXED, __HIP_MEMORY_SCOPE_AGENT);
          fqd[1] = __hip_atomic_load((u64*)(pa + ko3) + 1, __ATOMIC_RELAXED, __HIP_MEMORY_SCOPE_AGENT);
          const bf16x8 av0 = *(const bf16x8*)fqa;
          const bf16x8 av1 = *(const bf16x8*)fqb;
          const bf16x8 av2 = *(const bf16x8*)fqc;
          const bf16x8 av3 = *(const bf16x8*)fqd;
          {
            const u32* pw = &L.b.w1f[(size_t)(j0 * 16 + ks0) * 256 + lane];
            const u32x4 tw = {pw[0], pw[64], pw[128], pw[192]};
            acc0 = mfma16(av0, *(const bf16x8*)&tw, acc0);
          }
          {
            const u32* pw = &L.b.w1f[(size_t)(j1 * 16 + ks0) * 256 + lane];
            const u32x4 tw = {pw[0], pw[64], pw[128], pw[192]};
            acc1 = mfma16(av0, *(const bf16x8*)&tw, acc1);
          }
          {
            const u32* pw = &L.b.w1f[(size_t)(j0 * 16 + ks1) * 256 + lane];
            const u32x4 tw = {pw[0], pw[64], pw[128], pw[192]};
            acc0 = mfma16(av1, *(const bf16x8*)&tw, acc0);
          }
          {
            const u32* pw = &L.b.w1f[(size_t)(j1 * 16 + ks1) * 256 + lane];
            const u32x4 tw = {pw[0], pw[64], pw[128], pw[192]};
            acc1 = mfma16(av1, *(const bf16x8*)&tw, acc1);
          }
          {
            const u32* pw = &L.b.w1f[(size_t)(j0 * 16 + ks2) * 256 + lane];
            const u32x4 tw = {pw[0], pw[64], pw[128], pw[192]};
            acc0 = mfma16(av2, *(const bf16x8*)&tw, acc0);
          }
          {
            const u32* pw = &L.b.w1f[(size_t)(j1 * 16 + ks2) * 256 + lane];
            const u32x4 tw = {pw[0], pw[64], pw[128], pw[192]};
            acc1 = mfma16(av2, *(const bf16x8*)&tw, acc1);
          }
          {
            const u32* pw = &L.b.w1f[(size_t)(j0 * 16 + ks3) * 256 + lane];
            const u32x4 tw = {pw[0], pw[64], pw[128], pw[192]};
            acc0 = mfma16(av3, *(const bf16x8*)&tw, acc0);
          }
          {
            const u32* pw = &L.b.w1f[(size_t)(j1 * 16 + ks3) * 256 + lane];
            const u32x4 tw = {pw[0], pw[64], pw[128], pw[192]};
            acc1 = mfma16(av3, *(const bf16x8*)&tw, acc1);
          }
        }
        // relu + bias -> LDS restage (disjoint cols per pair-wave)
        {
          const int rb = wrow * 16 + q * 4;
          #pragma unroll
          for (int rg = 0; rg < 4; ++rg) {
            const int f0c = j0 * 16 + col16, f1c = j1 * 16 + col16;
            L.b.st[(rb + rg) * 72 + f0c] = (bf16_t)fmaxf(acc0[rg] + b1s[f0c], 0.f);
            L.b.st[(rb + rg) * 72 + f1c] = (bf16_t)fmaxf(acc1[rg] + b1s[f1c], 0.f);
          }
        }
        __syncthreads();
        for (int w = tid; w < 1024; w += NTHR) {
          const int r = w >> 4, cq = (w & 15) * 4;
          const u64 pk = *(const u64*)&L.b.st[r * 72 + cq];
          __hip_atomic_store((u64*)(hwid + (size_t)(b0 + r) * FFD + f0 + cq), pk,
                             __ATOMIC_RELAXED, __HIP_MEMORY_SCOPE_AGENT);
        }
      }
      if (u >= 1 && u <= TT) {             // FF2 consume: K-half per wave
        const int t = u - 1;
        f32x4 acc = {0.f, 0.f, 0.f, 0.f};
        const int kbase = whalf * 4;
        {
          u64 w0[2] = {fz0a, fz0b};
          const u32* pw = &L.b.w2f[(size_t)(kbase + 0) * 256 + lane];
          const u32x4 tw = {pw[0], pw[64], pw[128], pw[192]};
          acc = mfma16(*(const bf16x8*)w0, *(const bf16x8*)&tw, acc);
        }
        {
          u64 w1v[2] = {fz1a, fz1b};
          const u32* pw = &L.b.w2f[(size_t)(kbase + 1) * 256 + lane];
          const u32x4 tw = {pw[0], pw[64], pw[128], pw[192]};
          acc = mfma16(*(const bf16x8*)w1v, *(const bf16x8*)&tw, acc);
        }
        {
          u64 w2v[2] = {fz2a, fz2b};
          const u32* pw = &L.b.w2f[(size_t)(kbase + 2) * 256 + lane];
          const u32x4 tw = {pw[0], pw[64], pw[128], pw[192]};
          acc = mfma16(*(const bf16x8*)w2v, *(const bf16x8*)&tw, acc);
        }
        {
          u64 w3v[2] = {fz3a, fz3b};
          const u32* pw = &L.b.w2f[(size_t)(kbase + 3) * 256 + lane];
          const u32x4 tw = {pw[0], pw[64], pw[128], pw[192]};
          acc = mfma16(*(const bf16x8*)w3v, *(const bf16x8*)&tw, acc);
        }
        // K-halves from the wave-pair sum via pscr atomicAdd (existing path)
        float* pb = pg + (size_t)(t & 1) * PSLOT;
        #pragma unroll
        for (int rg = 0; rg < 4; ++rg)
          atomicAdd(pb + (wrow * 16 + q * 4 + rg) * 16 + col16, acc[rg]);
      }
      if (isFin && u >= 2 && tid < 256) {  // finalize consume (loads landed)
        const int t2 = u - 2;
        float pv[4];
        ((u64*)pv)[0] = fp0;
        ((u64*)pv)[1] = fp1;
        const int row = tid >> 2, c4 = (tid & 3) * 4;
        const bool v = (t2 < seqC[row]);
        float* po = out + ((size_t)(b0 + row) * TT + t2) * OUTD + o0 + c4;
        #pragma unroll
        for (int j = 0; j < 4; ++j)
          po[j] = v ? (pv[j] + b2s[c4 + j]) : PADV;
        // re-zero the slot for t = u (replay-safe, gated by flagB >= u+1)
        __hip_atomic_store((u64*)ppF,     0ull, __ATOMIC_RELAXED, __HIP_MEMORY_SCOPE_AGENT);
        __hip_atomic_store((u64*)ppF + 1, 0ull, __ATOMIC_RELAXED, __HIP_MEMORY_SCOPE_AGENT);
      }
      __syncthreads();                     // drain hd stores / adds / zeros
      if (tid == 0)
        __hip_atomic_store(&flagB[fc], (unsigned)(u + 1), __ATOMIC_RELAXED, __HIP_MEMORY_SCOPE_AGENT);
    }
  }
}

extern "C" void kernel_launch(void* const* d_in, const int* in_sizes, int n_in,
                              void* d_out, int out_size, void* d_ws, size_t ws_size,
                              hipStream_t stream) {
  const float* x   = (const float*)d_in[0];
  const int*   seq = (const int*)d_in[1];
  const float* Wih = (const float*)d_in[2];
  const float* Whh = (const float*)d_in[3];
  const float* bih = (const float*)d_in[4];
  const float* bhh = (const float*)d_in[5];
  const float* W1  = (const float*)d_in[6];
  const float* b1  = (const float*)d_in[7];
  const float* W2  = (const float*)d_in[8];
  const float* b2  = (const float*)d_in[9];
  float* out = (float*)d_out;
  char* ws = (char*)d_ws;

  unsigned* bar = (unsigned*)ws;                       // flag lines, 128B apart
  float* psc = (float*)(ws + 4096);                    // 2*PSLOT f32 = 256KB
  bf16_t* hb = (bf16_t*)(ws + 4096 + 2 * PSLOT * 4);   // h ping-pong  2*B*H
  bf16_t* ff = hb + (size_t)2 * BB * HDIM;             // ffin ping-pong
  bf16_t* hd = ff + (size_t)2 * BB * HDIM;             // hid ping-pong 2*B*FF
  // total scratch ~4.5 MB

  hipMemsetAsync(ws, 0, 4096 + 2 * PSLOT * 4, stream);
  void* args[] = {&x, &seq, &Wih, &Whh, &bih, &bhh, &W1, &b1, &W2, &b2,
                  &out, &hb, &ff, &hd, &psc, &bar};
  hipLaunchCooperativeKernel((void*)gru_net_kernel, dim3(NBLK), dim3(NTHR),
                             args, 0, stream);
}

// Round 12
// 2503.743 us; speedup vs baseline: 1.2952x; 1.2952x over previous
//
#include <hip/hip_runtime.h>

#define BB 512
#define TT 256
#define FDIM 128
#define HDIM 512
#define FFD 1024
#define OUTD 64
#define PADV -999.0f
#define NBLK 256
#define NTHR 256
#define PGRP (4 * 64 * 16)        // pscr floats per (group): 4 ocol x 64 rows x 16 cols
#define PSLOT (8 * PGRP)          // pscr floats per ping-pong slot (8 groups)

typedef __bf16 bf16_t;
typedef bf16_t bf16x8 __attribute__((ext_vector_type(8)));
typedef float f32x4 __attribute__((ext_vector_type(4)));
typedef unsigned int u32;
typedef u32 u32x4 __attribute__((ext_vector_type(4)));
typedef unsigned long long u64;

// R18 LDS layout: DWORD-PLANE fragments (bank-conflict-free; verified:
// SQ_LDS_BANK_CONFLICT 6.15e8 -> 1.05e7). dword d of lane l at dword index
// frag*256 + d*64 + l. R20 hprev: own h-slice stash in LDS.
union LdsU {
  struct {                        // A-role (GRU gates), 128 blocks
    u32 rzf[80 * 256];            // [j<4][ks<20: 0..3 x-part, 4..19 h-part]
    u32 nhf[32 * 256];            // [j2<2][ks<16] h_n (Whh rows 1024+)
    u32 nif[8 * 256];             // [j2<2][ks<4]  i_n (Wih rows 1024+)
    float  ex[4][64][33];         // gate exchange [r,z,nh,ni][row][col]
    u64 hprev[64][8];             // own (b0-rows x c0-cols) h slice
  } a;
  struct {                        // B-role (FF1 + FF2-chunk), 128 blocks
    u32 w1f[64 * 256];            // [j<4][ks<16]
    u32 w2f[8 * 256];             // [ks<8] own K-quarter of W2
    bf16_t st[64 * 72];           // FF1 output restage
  } b;
};

__device__ __forceinline__ f32x4 mfma16(bf16x8 a, bf16x8 b, f32x4 c) {
  return __builtin_amdgcn_mfma_f32_16x16x32_bf16(a, b, c, 0, 0, 0);
}
__device__ __forceinline__ float sigm(float x) { return 1.f / (1.f + __expf(-x)); }
__device__ __forceinline__ float tanh_f(float x) { return 2.f / (1.f + __expf(-2.f * x)) - 1.f; }

// R20 flag barrier: per-sibling monotone flag STORES + 32-lane parallel
// poll (wave 0 only): lanes 0-15 spin on f1[lane] >= v1, 16-31 on f2 >= v2.
__device__ __forceinline__ void wait_flags(unsigned* f1, unsigned v1,
                                           unsigned* f2, unsigned v2) {
  const int l = threadIdx.x & 63;
  if (l < 32) {
    unsigned* p = (l < 16) ? (f1 + l) : (f2 + (l - 16));
    const unsigned v = (l < 16) ? v1 : v2;
    while (__hip_atomic_load(p, __ATOMIC_RELAXED, __HIP_MEMORY_SCOPE_AGENT) < v)
      __builtin_amdgcn_s_sleep(1);
  }
}

// LESSONS (stub-failure = silent compile fail -> harness fallback):
//  1. __hip_atomic_* pointer args must be NON-CONST, used inline.
//  2. NO prefetch arrays >= 64 VGPRs feeding unrolled MFMA loops.
//  3. R12: inline-asm cache-flag loads -> stub fallback.
//  4. R12/13/14: load batching via asm / u64[16] arrays / MACROs -> stub.
//     Proven: named u64 q[2] pairs, adjacent loads INLINE (R16/R19/R20).
//  5. R16: wave K-split + NEW cross-wave reduction = 2.4x regression.
//     R21: 512-thr wave-pair split = +45% regression (duplicated loads,
//     2x pscr atomics) -> TLP/occupancy is NOT the lever either.
//  6. R17/R19 (load-group depth), R20 (flag barrier + epilogue hoist +
//     hprev): all ~null. R18 (bank-conflict fix): real -18%.
//  7. R22 theory: A and B legs (~4.5us each) partially serialize through
//     flagB, which B raises only after its FULL iteration (FF1 stores +
//     FF2 + finalize tail ~1.5-2us). A only needs "FF1(t-2) consumed
//     ff[t-2]" -> raise an EARLY flagC at FF1's post-restage barrier and
//     point A's back-pressure wait at it. flagB keeps B-internal role.
//
// Sync graph: flagA[g][sib] = t+2 after A iter t (1 after zero).
// flagB[g][fc] = u+1 after B iter u (B sibling sync: pscr slot zeroed,
// hd consumed). flagC[g][fc] = u+1 after FF1(u)'s loads are consumed
// (post-restage barrier). A(t) waits flagA>=t+1 & (t>=2) flagC>=t-1.
// B(u) waits flagB>=u & (u<TT) flagA>=u+2.

__global__ __launch_bounds__(NTHR) void gru_net_kernel(
    const float* __restrict__ x, const int* __restrict__ seq,
    const float* __restrict__ Wih, const float* __restrict__ Whh,
    const float* __restrict__ bih, const float* __restrict__ bhh,
    const float* __restrict__ W1, const float* __restrict__ b1,
    const float* __restrict__ W2, const float* __restrict__ b2,
    float* __restrict__ out,
    bf16_t* __restrict__ hb, bf16_t* __restrict__ ff, bf16_t* __restrict__ hd,
    float* __restrict__ psc, unsigned* __restrict__ bar) {
  __shared__ LdsU L;
  __shared__ float biasA[4][32];
  __shared__ float b1s[64];
  __shared__ float b2s[16];
  __shared__ int   seqA[64];
  __shared__ int   seqC[64];

  const int blk = blockIdx.x, tid = threadIdx.x;
  const int wv = tid >> 6, lane = tid & 63;
  const int q = lane >> 4, col16 = lane & 15, q8 = q * 8;
  const bool isA = blk < 128;

  const int grp = isA ? (blk & 7) : ((blk - 128) & 7);
  unsigned* flagA = bar + grp * 32;           // 16 u32 in a 128B line
  unsigned* flagB = bar + (8 + grp) * 32;
  unsigned* flagC = bar + (16 + grp) * 32;    // early FF1-consume signal

  int b0 = 0, c0 = 0, f0 = 0;
  if (isA) {
    const int sib = blk >> 3;      // sibling index 0..15 (h-col group)
    b0 = (blk & 7) * 64;           // batch row group (8)
    c0 = sib * 32;                 // h-col group (16)
    // rzf: frag fi=j*20+ks; lane(q,c) elem e = W[grow(j*16+c)][k], where
    // ks<4 -> Wih k=ks*32+q*8+e ; ks>=4 -> Whh k=(ks-4)*32+q*8+e
    for (int i = tid; i < 80 * 64; i += NTHR) {
      const int ln = i & 63, fi = i >> 6;
      const int j = fi / 20, ks = fi - j * 20;
      const int cc = ln & 15, qq = ln >> 4;
      const int colj = j * 16 + cc;
      const int grow = (colj < 32) ? (c0 + colj) : (512 + c0 + (colj - 32));
      bf16_t tmp[8];
      if (ks < 4) {
        const float* src = Wih + (size_t)grow * FDIM + ks * 32 + qq * 8;
        for (int e = 0; e < 8; ++e) tmp[e] = (bf16_t)src[e];
      } else {
        const float* src = Whh + (size_t)grow * HDIM + (ks - 4) * 32 + qq * 8;
        for (int e = 0; e < 8; ++e) tmp[e] = (bf16_t)src[e];
      }
      const u32* t32 = (const u32*)tmp;
      u32* dst = &L.a.rzf[fi * 256 + ln];
      dst[0] = t32[0]; dst[64] = t32[1]; dst[128] = t32[2]; dst[192] = t32[3];
    }
    for (int i = tid; i < 32 * 64; i += NTHR) {   // nhf: fi=j2*16+ks
      const int ln = i & 63, fi = i >> 6;
      const int j2 = fi >> 4, ks = fi & 15;
      const int cc = ln & 15, qq = ln >> 4;
      const int grow = 1024 + c0 + j2 * 16 + cc;
      const float* src = Whh + (size_t)grow * HDIM + ks * 32 + qq * 8;
      bf16_t tmp[8];
      for (int e = 0; e < 8; ++e) tmp[e] = (bf16_t)src[e];
      const u32* t32 = (const u32*)tmp;
      u32* dst = &L.a.nhf[fi * 256 + ln];
      dst[0] = t32[0]; dst[64] = t32[1]; dst[128] = t32[2]; dst[192] = t32[3];
    }
    for (int i = tid; i < 8 * 64; i += NTHR) {    // nif: fi=j2*4+ks
      const int ln = i & 63, fi = i >> 6;
      const int j2 = fi >> 2, ks = fi & 3;
      const int cc = ln & 15, qq = ln >> 4;
      const int grow = 1024 + c0 + j2 * 16 + cc;
      const float* src = Wih + (size_t)grow * FDIM + ks * 32 + qq * 8;
      bf16_t tmp[8];
      for (int e = 0; e < 8; ++e) tmp[e] = (bf16_t)src[e];
      const u32* t32 = (const u32*)tmp;
      u32* dst = &L.a.nif[fi * 256 + ln];
      dst[0] = t32[0]; dst[64] = t32[1]; dst[128] = t32[2]; dst[192] = t32[3];
    }
    if (tid < 32) {
      biasA[0][tid] = bih[c0 + tid] + bhh[c0 + tid];
      biasA[1][tid] = bih[512 + c0 + tid] + bhh[512 + c0 + tid];
      biasA[2][tid] = bih[1024 + c0 + tid];   // i_n bias
      biasA[3][tid] = bhh[1024 + c0 + tid];   // h_n bias
    }
    if (tid < 64) seqA[tid] = seq[b0 + tid];

    // zero OWN shard of h_{-1} (slot 1) + LDS hprev: 64 rows x 32 cols
    for (int i = tid; i < 512; i += NTHR) {
      const int r = i >> 3, cq = (i & 7) * 4;
      __hip_atomic_store((u64*)(hb + (size_t)BB * HDIM + (size_t)(b0 + r) * HDIM + c0 + cq),
                         0ull, __ATOMIC_RELAXED, __HIP_MEMORY_SCOPE_AGENT);
      ((u64*)L.a.hprev)[i] = 0ull;
    }
    __syncthreads();                         // drain zero stores + LDS staging
    if (tid == 0)
      __hip_atomic_store(&flagA[sib], 1u, __ATOMIC_RELAXED, __HIP_MEMORY_SCOPE_AGENT);

    // ---- A loop: one GRU timestep per iteration, group-local sync ----
    for (int t = 0; t < TT; ++t) {
      // --- pre-barrier: x-part (depends on t only; overlaps sibling wait) ---
      const int rA = b0 + wv * 16 + col16;
      const float* paxf = x + ((size_t)rA * TT + t) * FDIM;
      const f32x4 zz = {0.f, 0.f, 0.f, 0.f};
      f32x4 acc[4] = {zz, zz, zz, zz};
      f32x4 accn[2] = {zz, zz};
      f32x4 acci[2] = {zz, zz};
      #pragma unroll
      for (int ks = 0; ks < 4; ++ks) {
        const int ko = ks * 32 + q8;
        const float4 u0 = *(const float4*)(paxf + ko);
        const float4 u1 = *(const float4*)(paxf + ko + 4);
        bf16x8 av;
        av[0]=(bf16_t)u0.x; av[1]=(bf16_t)u0.y; av[2]=(bf16_t)u0.z; av[3]=(bf16_t)u0.w;
        av[4]=(bf16_t)u1.x; av[5]=(bf16_t)u1.y; av[6]=(bf16_t)u1.z; av[7]=(bf16_t)u1.w;
        #pragma unroll
        for (int j = 0; j < 4; ++j) {
          const u32* pz = &L.a.rzf[(size_t)(j * 20 + ks) * 256 + lane];
          const u32x4 tz = {pz[0], pz[64], pz[128], pz[192]};
          acc[j] = mfma16(av, *(const bf16x8*)&tz, acc[j]);
        }
        #pragma unroll
        for (int j = 0; j < 2; ++j) {
          const u32* pn = &L.a.nif[(size_t)(j * 4 + ks) * 256 + lane];
          const u32x4 tn = {pn[0], pn[64], pn[128], pn[192]};
          acci[j] = mfma16(av, *(const bf16x8*)&tn, acci[j]);
        }
      }
      // --- barrier: siblings done t-1 AND FF1(t-2) consumed ff[t-2] ---
      if (wv == 0)
        wait_flags(flagA, (unsigned)(t + 1), flagC, (t >= 2) ? (unsigned)(t - 1) : 0u);
      __syncthreads();

      bf16_t* hr = hb + (size_t)((t + 1) & 1) * BB * HDIM;
      bf16_t* hw = hb + (size_t)(t & 1) * BB * HDIM;
      bf16_t* fw = ff + (size_t)(t & 1) * BB * HDIM;
      bf16_t* pah = hr + (size_t)rA * HDIM;
      // h part: 16 ks in QUADS (4 named pairs, 8 adjacent loads per group)
      #pragma unroll
      for (int kp = 0; kp < 4; ++kp) {
        const int ks0 = kp * 4, ks1 = kp * 4 + 1, ks2 = kp * 4 + 2, ks3 = kp * 4 + 3;
        const int ko0 = ks0 * 32 + q8, ko1 = ks1 * 32 + q8;
        const int ko2 = ks2 * 32 + q8, ko3 = ks3 * 32 + q8;
        u64 hqa[2];
        u64 hqb[2];
        u64 hqc[2];
        u64 hqd[2];
        hqa[0] = __hip_atomic_load((u64*)(pah + ko0),     __ATOMIC_RELAXED, __HIP_MEMORY_SCOPE_AGENT);
        hqa[1] = __hip_atomic_load((u64*)(pah + ko0) + 1, __ATOMIC_RELAXED, __HIP_MEMORY_SCOPE_AGENT);
        hqb[0] = __hip_atomic_load((u64*)(pah + ko1),     __ATOMIC_RELAXED, __HIP_MEMORY_SCOPE_AGENT);
        hqb[1] = __hip_atomic_load((u64*)(pah + ko1) + 1, __ATOMIC_RELAXED, __HIP_MEMORY_SCOPE_AGENT);
        hqc[0] = __hip_atomic_load((u64*)(pah + ko2),     __ATOMIC_RELAXED, __HIP_MEMORY_SCOPE_AGENT);
        hqc[1] = __hip_atomic_load((u64*)(pah + ko2) + 1, __ATOMIC_RELAXED, __HIP_MEMORY_SCOPE_AGENT);
        hqd[0] = __hip_atomic_load((u64*)(pah + ko3),     __ATOMIC_RELAXED, __HIP_MEMORY_SCOPE_AGENT);
        hqd[1] = __hip_atomic_load((u64*)(pah + ko3) + 1, __ATOMIC_RELAXED, __HIP_MEMORY_SCOPE_AGENT);
        const bf16x8 av0 = *(const bf16x8*)hqa;
        const bf16x8 av1 = *(const bf16x8*)hqb;
        const bf16x8 av2 = *(const bf16x8*)hqc;
        const bf16x8 av3 = *(const bf16x8*)hqd;
        #pragma unroll
        for (int j = 0; j < 4; ++j) {
          const u32* pz = &L.a.rzf[(size_t)(j * 20 + 4 + ks0) * 256 + lane];
          const u32x4 tz = {pz[0], pz[64], pz[128], pz[192]};
          acc[j] = mfma16(av0, *(const bf16x8*)&tz, acc[j]);
        }
        #pragma unroll
        for (int j = 0; j < 2; ++j) {
          const u32* pn = &L.a.nhf[(size_t)(j * 16 + ks0) * 256 + lane];
          const u32x4 tn = {pn[0], pn[64], pn[128], pn[192]};
          accn[j] = mfma16(av0, *(const bf16x8*)&tn, accn[j]);
        }
        #pragma unroll
        for (int j = 0; j < 4; ++j) {
          const u32* pz = &L.a.rzf[(size_t)(j * 20 + 4 + ks1) * 256 + lane];
          const u32x4 tz = {pz[0], pz[64], pz[128], pz[192]};
          acc[j] = mfma16(av1, *(const bf16x8*)&tz, acc[j]);
        }
        #pragma unroll
        for (int j = 0; j < 2; ++j) {
          const u32* pn = &L.a.nhf[(size_t)(j * 16 + ks1) * 256 + lane];
          const u32x4 tn = {pn[0], pn[64], pn[128], pn[192]};
          accn[j] = mfma16(av1, *(const bf16x8*)&tn, accn[j]);
        }
        #pragma unroll
        for (int j = 0; j < 4; ++j) {
          const u32* pz = &L.a.rzf[(size_t)(j * 20 + 4 + ks2) * 256 + lane];
          const u32x4 tz = {pz[0], pz[64], pz[128], pz[192]};
          acc[j] = mfma16(av2, *(const bf16x8*)&tz, acc[j]);
        }
        #pragma unroll
        for (int j = 0; j < 2; ++j) {
          const u32* pn = &L.a.nhf[(size_t)(j * 16 + ks2) * 256 + lane];
          const u32x4 tn = {pn[0], pn[64], pn[128], pn[192]};
          accn[j] = mfma16(av2, *(const bf16x8*)&tn, accn[j]);
        }
        #pragma unroll
        for (int j = 0; j < 4; ++j) {
          const u32* pz = &L.a.rzf[(size_t)(j * 20 + 4 + ks3) * 256 + lane];
          const u32x4 tz = {pz[0], pz[64], pz[128], pz[192]};
          acc[j] = mfma16(av3, *(const bf16x8*)&tz, acc[j]);
        }
        #pragma unroll
        for (int j = 0; j < 2; ++j) {
          const u32* pn = &L.a.nhf[(size_t)(j * 16 + ks3) * 256 + lane];
          const u32x4 tn = {pn[0], pn[64], pn[128], pn[192]};
          accn[j] = mfma16(av3, *(const bf16x8*)&tn, accn[j]);
        }
      }
      // dump gate sums to LDS exchange (C/D: col=lane&15, row=q*4+reg)
      #pragma unroll
      for (int j = 0; j < 4; ++j) {
        const int sl = j >> 1, cb = (j & 1) * 16 + col16;
        #pragma unroll
        for (int rg = 0; rg < 4; ++rg)
          L.a.ex[sl][wv * 16 + q * 4 + rg][cb] = acc[j][rg];
      }
      #pragma unroll
      for (int j = 0; j < 2; ++j) {
        const int cb = j * 16 + col16;
        #pragma unroll
        for (int rg = 0; rg < 4; ++rg) {
          L.a.ex[2][wv * 16 + q * 4 + rg][cb] = accn[j][rg];
          L.a.ex[3][wv * 16 + q * 4 + rg][cb] = acci[j][rg];
        }
      }
      __syncthreads();
      // elementwise GRU update: h_prev from LDS stash (no global RT)
      for (int e = tid; e < 512; e += NTHR) {
        const int row = e >> 3, cq = (e & 7) << 2;
        const int bidx = b0 + row;
        const u64 hp8 = L.a.hprev[row][cq >> 2];
        const bf16_t* hp4 = (const bf16_t*)&hp8;
        bf16_t hw4[4], fw4[4];
        const bool v = (t < seqA[row]);
        #pragma unroll
        for (int j = 0; j < 4; ++j) {
          const int c = cq + j;
          const float gr  = L.a.ex[0][row][c] + biasA[0][c];
          const float gz  = L.a.ex[1][row][c] + biasA[1][c];
          const float gnh = L.a.ex[2][row][c] + biasA[3][c];
          const float gni = L.a.ex[3][row][c] + biasA[2][c];
          const float r = sigm(gr), zg = sigm(gz);
          const float n = tanh_f(gni + r * gnh);
          const float hp = (float)hp4[j];
          const float hnew = (1.f - zg) * n + zg * hp;
          hw4[j] = (bf16_t)(v ? hnew : hp);
          fw4[j] = (bf16_t)(v ? hnew : 0.f);
        }
        L.a.hprev[row][cq >> 2] = *(u64*)hw4;
        __hip_atomic_store((u64*)(hw + (size_t)bidx * HDIM + c0 + cq), *(u64*)hw4,
                           __ATOMIC_RELAXED, __HIP_MEMORY_SCOPE_AGENT);
        __hip_atomic_store((u64*)(fw + (size_t)bidx * HDIM + c0 + cq), *(u64*)fw4,
                           __ATOMIC_RELAXED, __HIP_MEMORY_SCOPE_AGENT);
      }
      __syncthreads();                       // drain h/ff stores
      if (tid == 0)
        __hip_atomic_store(&flagA[sib], (unsigned)(t + 2), __ATOMIC_RELAXED, __HIP_MEMORY_SCOPE_AGENT);
    }
  } else {
    const int cidx = blk - 128;
    const int fc = cidx >> 3;      // 0..15 (sibling index)
    const int oc = fc & 3;         // out-col group (4 x 16 cols)
    const int kq = fc >> 2;        // K-quarter (4 x 256)
    const bool isFin = (fc < 4);   // finalizer blocks (one per (g, oc))
    b0 = (cidx & 7) * 64;          // batch group (same XCD residue as A)
    f0 = fc * 64;                  // FF col group (16)
    const int o0 = oc * 16;
    for (int i = tid; i < 64 * 64; i += NTHR) {   // w1f: fi=j*16+ks
      const int ln = i & 63, fi = i >> 6;
      const int j = fi >> 4, ks = fi & 15;
      const int cc = ln & 15, qq = ln >> 4;
      const int fcol = f0 + j * 16 + cc;
      const int kb = ks * 32 + qq * 8;
      bf16_t tmp[8];
      for (int e = 0; e < 8; ++e) tmp[e] = (bf16_t)W1[(size_t)(kb + e) * FFD + fcol];
      const u32* t32 = (const u32*)tmp;
      u32* dst = &L.b.w1f[fi * 256 + ln];
      dst[0] = t32[0]; dst[64] = t32[1]; dst[128] = t32[2]; dst[192] = t32[3];
    }
    if (tid < 64) b1s[tid] = b1[f0 + tid];
    for (int i = tid; i < 8 * 64; i += NTHR) {    // w2f: own K-quarter, fi=ks<8
      const int ln = i & 63, ks = i >> 6;
      const int cc = ln & 15, qq = ln >> 4;
      const int kb = kq * 256 + ks * 32 + qq * 8;
      bf16_t tmp[8];
      for (int e = 0; e < 8; ++e) tmp[e] = (bf16_t)W2[(kb + e) * OUTD + o0 + cc];
      const u32* t32 = (const u32*)tmp;
      u32* dst = &L.b.w2f[ks * 256 + ln];
      dst[0] = t32[0]; dst[64] = t32[1]; dst[128] = t32[2]; dst[192] = t32[3];
    }
    if (isFin) {
      if (tid < 16) b2s[tid] = b2[o0 + tid];
      if (tid < 64) seqC[tid] = seq[b0 + tid];
    }
    __syncthreads();               // LDS staging visible block-wide

    // ---- B loop: iter u = FF1(t=u), FF2-chunk adds(t=u-1), finalize(t=u-2)
    float* pg = psc + (size_t)grp * PGRP + (size_t)oc * (64 * 16);
    for (int u = 0; u <= TT + 1; ++u) {
      if (wv == 0)
        wait_flags(flagB, (unsigned)u, flagA, (u < TT) ? (unsigned)(u + 2) : 0u);
      __syncthreads();

      // --- hoisted issue: FF2 fragment loads (t=u-1; inputs ready at head)
      const int rCF = b0 + wv * 16 + col16;
      bf16_t* paF = hd + (size_t)((u - 1) & 1) * BB * FFD + (size_t)rCF * FFD + kq * 256 + q8;
      u64 fz0a = 0, fz0b = 0, fz1a = 0, fz1b = 0, fz2a = 0, fz2b = 0, fz3a = 0, fz3b = 0;
      u64 fz4a = 0, fz4b = 0, fz5a = 0, fz5b = 0, fz6a = 0, fz6b = 0, fz7a = 0, fz7b = 0;
      if (u >= 1 && u <= TT) {
        fz0a = __hip_atomic_load((u64*)(paF + 0 * 32),     __ATOMIC_RELAXED, __HIP_MEMORY_SCOPE_AGENT);
        fz0b = __hip_atomic_load((u64*)(paF + 0 * 32) + 1, __ATOMIC_RELAXED, __HIP_MEMORY_SCOPE_AGENT);
        fz1a = __hip_atomic_load((u64*)(paF + 1 * 32),     __ATOMIC_RELAXED, __HIP_MEMORY_SCOPE_AGENT);
        fz1b = __hip_atomic_load((u64*)(paF + 1 * 32) + 1, __ATOMIC_RELAXED, __HIP_MEMORY_SCOPE_AGENT);
        fz2a = __hip_atomic_load((u64*)(paF + 2 * 32),     __ATOMIC_RELAXED, __HIP_MEMORY_SCOPE_AGENT);
        fz2b = __hip_atomic_load((u64*)(paF + 2 * 32) + 1, __ATOMIC_RELAXED, __HIP_MEMORY_SCOPE_AGENT);
        fz3a = __hip_atomic_load((u64*)(paF + 3 * 32),     __ATOMIC_RELAXED, __HIP_MEMORY_SCOPE_AGENT);
        fz3b = __hip_atomic_load((u64*)(paF + 3 * 32) + 1, __ATOMIC_RELAXED, __HIP_MEMORY_SCOPE_AGENT);
        fz4a = __hip_atomic_load((u64*)(paF + 4 * 32),     __ATOMIC_RELAXED, __HIP_MEMORY_SCOPE_AGENT);
        fz4b = __hip_atomic_load((u64*)(paF + 4 * 32) + 1, __ATOMIC_RELAXED, __HIP_MEMORY_SCOPE_AGENT);
        fz5a = __hip_atomic_load((u64*)(paF + 5 * 32),     __ATOMIC_RELAXED, __HIP_MEMORY_SCOPE_AGENT);
        fz5b = __hip_atomic_load((u64*)(paF + 5 * 32) + 1, __ATOMIC_RELAXED, __HIP_MEMORY_SCOPE_AGENT);
        fz6a = __hip_atomic_load((u64*)(paF + 6 * 32),     __ATOMIC_RELAXED, __HIP_MEMORY_SCOPE_AGENT);
        fz6b = __hip_atomic_load((u64*)(paF + 6 * 32) + 1, __ATOMIC_RELAXED, __HIP_MEMORY_SCOPE_AGENT);
        fz7a = __hip_atomic_load((u64*)(paF + 7 * 32),     __ATOMIC_RELAXED, __HIP_MEMORY_SCOPE_AGENT);
        fz7b = __hip_atomic_load((u64*)(paF + 7 * 32) + 1, __ATOMIC_RELAXED, __HIP_MEMORY_SCOPE_AGENT);
      }
      // --- hoisted issue: finalize pscr loads (t2=u-2; ready at head)
      float* ppF = pg + (size_t)((u - 2) & 1) * PSLOT + (tid >> 2) * 16 + (tid & 3) * 4;
      u64 fp0 = 0, fp1 = 0;
      if (isFin && u >= 2) {
        fp0 = __hip_atomic_load((u64*)ppF,     __ATOMIC_RELAXED, __HIP_MEMORY_SCOPE_AGENT);
        fp1 = __hip_atomic_load((u64*)ppF + 1, __ATOMIC_RELAXED, __HIP_MEMORY_SCOPE_AGENT);
      }

      if (u < TT) {                        // FF1 for t = u; 16 ks in 4 quads
        const int t = u;
        bf16_t* fr = ff + (size_t)(t & 1) * BB * HDIM;
        bf16_t* hwid = hd + (size_t)(t & 1) * BB * FFD;
        const int rB = b0 + wv * 16 + col16;
        bf16_t* pa = fr + (size_t)rB * HDIM;
        const f32x4 zz = {0.f, 0.f, 0.f, 0.f};
        f32x4 acc[4] = {zz, zz, zz, zz};
        #pragma unroll
        for (int kp = 0; kp < 4; ++kp) {
          const int ks0 = kp * 4, ks1 = kp * 4 + 1, ks2 = kp * 4 + 2, ks3 = kp * 4 + 3;
          const int ko0 = ks0 * 32 + q8, ko1 = ks1 * 32 + q8;
          const int ko2 = ks2 * 32 + q8, ko3 = ks3 * 32 + q8;
          u64 fqa[2];
          u64 fqb[2];
          u64 fqc[2];
          u64 fqd[2];
          fqa[0] = __hip_atomic_load((u64*)(pa + ko0),     __ATOMIC_RELAXED, __HIP_MEMORY_SCOPE_AGENT);
          fqa[1] = __hip_atomic_load((u64*)(pa + ko0) + 1, __ATOMIC_RELAXED, __HIP_MEMORY_SCOPE_AGENT);
          fqb[0] = __hip_atomic_load((u64*)(pa + ko1),     __ATOMIC_RELAXED, __HIP_MEMORY_SCOPE_AGENT);
          fqb[1] = __hip_atomic_load((u64*)(pa + ko1) + 1, __ATOMIC_RELAXED, __HIP_MEMORY_SCOPE_AGENT);
          fqc[0] = __hip_atomic_load((u64*)(pa + ko2),     __ATOMIC_RELAXED, __HIP_MEMORY_SCOPE_AGENT);
          fqc[1] = __hip_atomic_load((u64*)(pa + ko2) + 1, __ATOMIC_RELAXED, __HIP_MEMORY_SCOPE_AGENT);
          fqd[0] = __hip_atomic_load((u64*)(pa + ko3),     __ATOMIC_RELAXED, __HIP_MEMORY_SCOPE_AGENT);
          fqd[1] = __hip_atomic_load((u64*)(pa + ko3) + 1, __ATOMIC_RELAXED, __HIP_MEMORY_SCOPE_AGENT);
          const bf16x8 av0 = *(const bf16x8*)fqa;
          const bf16x8 av1 = *(const bf16x8*)fqb;
          const bf16x8 av2 = *(const bf16x8*)fqc;
          const bf16x8 av3 = *(const bf16x8*)fqd;
          #pragma unroll
          for (int j = 0; j < 4; ++j) {
            const u32* pw = &L.b.w1f[(size_t)(j * 16 + ks0) * 256 + lane];
            const u32x4 tw = {pw[0], pw[64], pw[128], pw[192]};
            acc[j] = mfma16(av0, *(const bf16x8*)&tw, acc[j]);
          }
          #pragma unroll
          for (int j = 0; j < 4; ++j) {
            const u32* pw = &L.b.w1f[(size_t)(j * 16 + ks1) * 256 + lane];
            const u32x4 tw = {pw[0], pw[64], pw[128], pw[192]};
            acc[j] = mfma16(av1, *(const bf16x8*)&tw, acc[j]);
          }
          #pragma unroll
          for (int j = 0; j < 4; ++j) {
            const u32* pw = &L.b.w1f[(size_t)(j * 16 + ks2) * 256 + lane];
            const u32x4 tw = {pw[0], pw[64], pw[128], pw[192]};
            acc[j] = mfma16(av2, *(const bf16x8*)&tw, acc[j]);
          }
          #pragma unroll
          for (int j = 0; j < 4; ++j) {
            const u32* pw = &L.b.w1f[(size_t)(j * 16 + ks3) * 256 + lane];
            const u32x4 tw = {pw[0], pw[64], pw[128], pw[192]};
            acc[j] = mfma16(av3, *(const bf16x8*)&tw, acc[j]);
          }
        }
        // relu + bias -> LDS restage -> contiguous 8B coherent stores
        #pragma unroll
        for (int j = 0; j < 4; ++j) {
          const int fcc = j * 16 + col16;
          #pragma unroll
          for (int rg = 0; rg < 4; ++rg)
            L.b.st[(wv * 16 + q * 4 + rg) * 72 + fcc] =
                (bf16_t)fmaxf(acc[j][rg] + b1s[fcc], 0.f);
        }
        __syncthreads();
        // EARLY SIGNAL: all waves are past their ff[u] loads (consumed into
        // MFMAs above) -> A may overwrite ff slot u&1 two steps from now.
        if (tid == 0)
          __hip_atomic_store(&flagC[fc], (unsigned)(u + 1), __ATOMIC_RELAXED, __HIP_MEMORY_SCOPE_AGENT);
        for (int w = tid; w < 1024; w += NTHR) {
          const int r = w >> 4, cq = (w & 15) * 4;
          const u64 pk = *(const u64*)&L.b.st[r * 72 + cq];
          __hip_atomic_store((u64*)(hwid + (size_t)(b0 + r) * FFD + f0 + cq), pk,
                             __ATOMIC_RELAXED, __HIP_MEMORY_SCOPE_AGENT);
        }
      }
      if (u >= 1 && u <= TT) {             // FF2 consume (loads landed)
        const int t = u - 1;
        f32x4 acc = {0.f, 0.f, 0.f, 0.f};
        {
          u64 w0[2] = {fz0a, fz0b};
          const u32* pw = &L.b.w2f[(size_t)0 * 256 + lane];
          const u32x4 tw = {pw[0], pw[64], pw[128], pw[192]};
          acc = mfma16(*(const bf16x8*)w0, *(const bf16x8*)&tw, acc);
        }
        {
          u64 w1v[2] = {fz1a, fz1b};
          const u32* pw = &L.b.w2f[(size_t)1 * 256 + lane];
          const u32x4 tw = {pw[0], pw[64], pw[128], pw[192]};
          acc = mfma16(*(const bf16x8*)w1v, *(const bf16x8*)&tw, acc);
        }
        {
          u64 w2v[2] = {fz2a, fz2b};
          const u32* pw = &L.b.w2f[(size_t)2 * 256 + lane];
          const u32x4 tw = {pw[0], pw[64], pw[128], pw[192]};
          acc = mfma16(*(const bf16x8*)w2v, *(const bf16x8*)&tw, acc);
        }
        {
          u64 w3v[2] = {fz3a, fz3b};
          const u32* pw = &L.b.w2f[(size_t)3 * 256 + lane];
          const u32x4 tw = {pw[0], pw[64], pw[128], pw[192]};
          acc = mfma16(*(const bf16x8*)w3v, *(const bf16x8*)&tw, acc);
        }
        {
          u64 w4v[2] = {fz4a, fz4b};
          const u32* pw = &L.b.w2f[(size_t)4 * 256 + lane];
          const u32x4 tw = {pw[0], pw[64], pw[128], pw[192]};
          acc = mfma16(*(const bf16x8*)w4v, *(const bf16x8*)&tw, acc);
        }
        {
          u64 w5v[2] = {fz5a, fz5b};
          const u32* pw = &L.b.w2f[(size_t)5 * 256 + lane];
          const u32x4 tw = {pw[0], pw[64], pw[128], pw[192]};
          acc = mfma16(*(const bf16x8*)w5v, *(const bf16x8*)&tw, acc);
        }
        {
          u64 w6v[2] = {fz6a, fz6b};
          const u32* pw = &L.b.w2f[(size_t)6 * 256 + lane];
          const u32x4 tw = {pw[0], pw[64], pw[128], pw[192]};
          acc = mfma16(*(const bf16x8*)w6v, *(const bf16x8*)&tw, acc);
        }
        {
          u64 w7v[2] = {fz7a, fz7b};
          const u32* pw = &L.b.w2f[(size_t)7 * 256 + lane];
          const u32x4 tw = {pw[0], pw[64], pw[128], pw[192]};
          acc = mfma16(*(const bf16x8*)w7v, *(const bf16x8*)&tw, acc);
        }
        float* pb = pg + (size_t)(t & 1) * PSLOT;
        #pragma unroll
        for (int rg = 0; rg < 4; ++rg)
          atomicAdd(pb + (wv * 16 + q * 4 + rg) * 16 + col16, acc[rg]);
      }
      if (isFin && u >= 2) {               // finalize consume (loads landed)
        const int t2 = u - 2;
        float pv[4];
        ((u64*)pv)[0] = fp0;
        ((u64*)pv)[1] = fp1;
        const int row = tid >> 2, c4 = (tid & 3) * 4;
        const bool v = (t2 < seqC[row]);
        float* po = out + ((size_t)(b0 + row) * TT + t2) * OUTD + o0 + c4;
        #pragma unroll
        for (int j = 0; j < 4; ++j)
          po[j] = v ? (pv[j] + b2s[c4 + j]) : PADV;
        // re-zero the slot for t = u (replay-safe, gated by flagB >= u+1)
        __hip_atomic_store((u64*)ppF,     0ull, __ATOMIC_RELAXED, __HIP_MEMORY_SCOPE_AGENT);
        __hip_atomic_store((u64*)ppF + 1, 0ull, __ATOMIC_RELAXED, __HIP_MEMORY_SCOPE_AGENT);
      }
      __syncthreads();                     // drain hd stores / adds / zeros
      if (tid == 0)
        __hip_atomic_store(&flagB[fc], (unsigned)(u + 1), __ATOMIC_RELAXED, __HIP_MEMORY_SCOPE_AGENT);
    }
  }
}

extern "C" void kernel_launch(void* const* d_in, const int* in_sizes, int n_in,
                              void* d_out, int out_size, void* d_ws, size_t ws_size,
                              hipStream_t stream) {
  const float* x   = (const float*)d_in[0];
  const int*   seq = (const int*)d_in[1];
  const float* Wih = (const float*)d_in[2];
  const float* Whh = (const float*)d_in[3];
  const float* bih = (const float*)d_in[4];
  const float* bhh = (const float*)d_in[5];
  const float* W1  = (const float*)d_in[6];
  const float* b1  = (const float*)d_in[7];
  const float* W2  = (const float*)d_in[8];
  const float* b2  = (const float*)d_in[9];
  float* out = (float*)d_out;
  char* ws = (char*)d_ws;

  unsigned* bar = (unsigned*)ws;                       // flag lines, 128B apart
  float* psc = (float*)(ws + 4096);                    // 2*PSLOT f32 = 256KB
  bf16_t* hb = (bf16_t*)(ws + 4096 + 2 * PSLOT * 4);   // h ping-pong  2*B*H
  bf16_t* ff = hb + (size_t)2 * BB * HDIM;             // ffin ping-pong
  bf16_t* hd = ff + (size_t)2 * BB * HDIM;             // hid ping-pong 2*B*FF
  // total scratch ~4.5 MB

  hipMemsetAsync(ws, 0, 4096 + 2 * PSLOT * 4, stream);
  void* args[] = {&x, &seq, &Wih, &Whh, &bih, &bhh, &W1, &b1, &W2, &b2,
                  &out, &hb, &ff, &hd, &psc, &bar};
  hipLaunchCooperativeKernel((void*)gru_net_kernel, dim3(NBLK), dim3(NTHR),
                             args, 0, stream);
}

// Round 13
// 2088.937 us; speedup vs baseline: 1.5524x; 1.1986x over previous
//
#include <hip/hip_runtime.h>

#define BB 512
#define TT 256
#define FDIM 128
#define HDIM 512
#define FFD 1024
#define OUTD 64
#define PADV -999.0f
#define NBLK 256
#define NTHR 256
#define PGRP (4 * 64 * 16)        // pscr floats per (group): 4 ocol x 64 rows x 16 cols
#define PSLOT (8 * PGRP)          // pscr floats per ping-pong slot (8 groups)

typedef __bf16 bf16_t;
typedef bf16_t bf16x8 __attribute__((ext_vector_type(8)));
typedef float f32x4 __attribute__((ext_vector_type(4)));
typedef unsigned int u32;
typedef u32 u32x4 __attribute__((ext_vector_type(4)));
typedef unsigned long long u64;

// R18 LDS layout: DWORD-PLANE fragments (bank-conflict-free; verified:
// SQ_LDS_BANK_CONFLICT 6.15e8 -> 1.05e7). dword d of lane l at dword index
// frag*256 + d*64 + l. R20 hprev: own h-slice stash in LDS.
union LdsU {
  struct {                        // A-role (GRU gates), 128 blocks
    u32 rzf[80 * 256];            // [j<4][ks<20: 0..3 x-part, 4..19 h-part]
    u32 nhf[32 * 256];            // [j2<2][ks<16] h_n (Whh rows 1024+)
    u32 nif[8 * 256];             // [j2<2][ks<4]  i_n (Wih rows 1024+)
    float  ex[4][64][33];         // gate exchange [r,z,nh,ni][row][col]
    u64 hprev[64][8];             // own (b0-rows x c0-cols) h slice
  } a;
  struct {                        // B-role (FF1 + FF2-chunk), 128 blocks
    u32 w1f[64 * 256];            // [j<4][ks<16]
    u32 w2f[8 * 256];             // [ks<8] own K-quarter of W2
    bf16_t st[64 * 72];           // FF1 output restage
  } b;
};

__device__ __forceinline__ f32x4 mfma16(bf16x8 a, bf16x8 b, f32x4 c) {
  return __builtin_amdgcn_mfma_f32_16x16x32_bf16(a, b, c, 0, 0, 0);
}
__device__ __forceinline__ float sigm(float x) { return 1.f / (1.f + __expf(-x)); }
__device__ __forceinline__ float tanh_f(float x) { return 2.f / (1.f + __expf(-2.f * x)) - 1.f; }

// R20 flag barrier: per-sibling monotone flag STORES + 32-lane parallel
// poll (wave 0 only): lanes 0-15 spin on f1[lane] >= v1, 16-31 on f2 >= v2.
__device__ __forceinline__ void wait_flags(unsigned* f1, unsigned v1,
                                           unsigned* f2, unsigned v2) {
  const int l = threadIdx.x & 63;
  if (l < 32) {
    unsigned* p = (l < 16) ? (f1 + l) : (f2 + (l - 16));
    const unsigned v = (l < 16) ? v1 : v2;
    while (__hip_atomic_load(p, __ATOMIC_RELAXED, __HIP_MEMORY_SCOPE_AGENT) < v)
      __builtin_amdgcn_s_sleep(1);
  }
}

// LESSONS (stub-failure = silent compile fail -> harness fallback):
//  1. __hip_atomic_* pointer args must be NON-CONST, used inline.
//  2. NO prefetch arrays >= 64 VGPRs feeding unrolled MFMA loops.
//  3. R12: inline-asm cache-flag loads -> stub fallback.
//  4. R12/13/14: load batching via asm / u64[16] arrays / MACROs -> stub.
//     Proven: named u64 q[2] pairs, adjacent loads INLINE (R16/R19/R20).
//  5. R16: wave K-split + NEW cross-wave reduction = 2.4x regression.
//     R21: 512-thr wave-pair split = +45% (duplicated loads, 2x atomics).
//     R22: early flagC (A runs ahead into B's tail) = +12% -> B is the
//     pacing leg; extra A concurrency during B's tail HURTS. A-slack is
//     anti-productive; shorten B's own iteration instead.
//  6. R17/R19 (load-group depth), R20 (flag barrier + epilogue hoist +
//     hprev): ~null. R18 (bank-conflict fix): real -18%.
//  7. R23: B's 4 isFin siblings did FF1+FF2+ALL finalize work -> sibling
//     barrier waits for them every iter (straggler-max). Split finalize
//     (4096 elems/group) evenly: 256 elems per sibling = 1 elem/thread.
//     All 16 B-siblings now have identical work.
//
// Sync graph (R20): flagA[g][sib] = t+2 after A iter t (1 after zero).
// flagB[g][fc] = u+1 after B iter u. A(t) waits flagA>=t+1 & (t>=2)
// flagB>=t-1. B(u) waits flagB>=u & (u<TT) flagA>=u+2.

__global__ __launch_bounds__(NTHR) void gru_net_kernel(
    const float* __restrict__ x, const int* __restrict__ seq,
    const float* __restrict__ Wih, const float* __restrict__ Whh,
    const float* __restrict__ bih, const float* __restrict__ bhh,
    const float* __restrict__ W1, const float* __restrict__ b1,
    const float* __restrict__ W2, const float* __restrict__ b2,
    float* __restrict__ out,
    bf16_t* __restrict__ hb, bf16_t* __restrict__ ff, bf16_t* __restrict__ hd,
    float* __restrict__ psc, unsigned* __restrict__ bar) {
  __shared__ LdsU L;
  __shared__ float biasA[4][32];
  __shared__ float b1s[64];
  __shared__ float b2s[64];
  __shared__ int   seqA[64];
  __shared__ int   seqC[64];

  const int blk = blockIdx.x, tid = threadIdx.x;
  const int wv = tid >> 6, lane = tid & 63;
  const int q = lane >> 4, col16 = lane & 15, q8 = q * 8;
  const bool isA = blk < 128;

  const int grp = isA ? (blk & 7) : ((blk - 128) & 7);
  unsigned* flagA = bar + grp * 32;           // 16 u32 in a 128B line
  unsigned* flagB = bar + (8 + grp) * 32;

  int b0 = 0, c0 = 0, f0 = 0;
  if (isA) {
    const int sib = blk >> 3;      // sibling index 0..15 (h-col group)
    b0 = (blk & 7) * 64;           // batch row group (8)
    c0 = sib * 32;                 // h-col group (16)
    // rzf: frag fi=j*20+ks; lane(q,c) elem e = W[grow(j*16+c)][k], where
    // ks<4 -> Wih k=ks*32+q*8+e ; ks>=4 -> Whh k=(ks-4)*32+q*8+e
    for (int i = tid; i < 80 * 64; i += NTHR) {
      const int ln = i & 63, fi = i >> 6;
      const int j = fi / 20, ks = fi - j * 20;
      const int cc = ln & 15, qq = ln >> 4;
      const int colj = j * 16 + cc;
      const int grow = (colj < 32) ? (c0 + colj) : (512 + c0 + (colj - 32));
      bf16_t tmp[8];
      if (ks < 4) {
        const float* src = Wih + (size_t)grow * FDIM + ks * 32 + qq * 8;
        for (int e = 0; e < 8; ++e) tmp[e] = (bf16_t)src[e];
      } else {
        const float* src = Whh + (size_t)grow * HDIM + (ks - 4) * 32 + qq * 8;
        for (int e = 0; e < 8; ++e) tmp[e] = (bf16_t)src[e];
      }
      const u32* t32 = (const u32*)tmp;
      u32* dst = &L.a.rzf[fi * 256 + ln];
      dst[0] = t32[0]; dst[64] = t32[1]; dst[128] = t32[2]; dst[192] = t32[3];
    }
    for (int i = tid; i < 32 * 64; i += NTHR) {   // nhf: fi=j2*16+ks
      const int ln = i & 63, fi = i >> 6;
      const int j2 = fi >> 4, ks = fi & 15;
      const int cc = ln & 15, qq = ln >> 4;
      const int grow = 1024 + c0 + j2 * 16 + cc;
      const float* src = Whh + (size_t)grow * HDIM + ks * 32 + qq * 8;
      bf16_t tmp[8];
      for (int e = 0; e < 8; ++e) tmp[e] = (bf16_t)src[e];
      const u32* t32 = (const u32*)tmp;
      u32* dst = &L.a.nhf[fi * 256 + ln];
      dst[0] = t32[0]; dst[64] = t32[1]; dst[128] = t32[2]; dst[192] = t32[3];
    }
    for (int i = tid; i < 8 * 64; i += NTHR) {    // nif: fi=j2*4+ks
      const int ln = i & 63, fi = i >> 6;
      const int j2 = fi >> 2, ks = fi & 3;
      const int cc = ln & 15, qq = ln >> 4;
      const int grow = 1024 + c0 + j2 * 16 + cc;
      const float* src = Wih + (size_t)grow * FDIM + ks * 32 + qq * 8;
      bf16_t tmp[8];
      for (int e = 0; e < 8; ++e) tmp[e] = (bf16_t)src[e];
      const u32* t32 = (const u32*)tmp;
      u32* dst = &L.a.nif[fi * 256 + ln];
      dst[0] = t32[0]; dst[64] = t32[1]; dst[128] = t32[2]; dst[192] = t32[3];
    }
    if (tid < 32) {
      biasA[0][tid] = bih[c0 + tid] + bhh[c0 + tid];
      biasA[1][tid] = bih[512 + c0 + tid] + bhh[512 + c0 + tid];
      biasA[2][tid] = bih[1024 + c0 + tid];   // i_n bias
      biasA[3][tid] = bhh[1024 + c0 + tid];   // h_n bias
    }
    if (tid < 64) seqA[tid] = seq[b0 + tid];

    // zero OWN shard of h_{-1} (slot 1) + LDS hprev: 64 rows x 32 cols
    for (int i = tid; i < 512; i += NTHR) {
      const int r = i >> 3, cq = (i & 7) * 4;
      __hip_atomic_store((u64*)(hb + (size_t)BB * HDIM + (size_t)(b0 + r) * HDIM + c0 + cq),
                         0ull, __ATOMIC_RELAXED, __HIP_MEMORY_SCOPE_AGENT);
      ((u64*)L.a.hprev)[i] = 0ull;
    }
    __syncthreads();                         // drain zero stores + LDS staging
    if (tid == 0)
      __hip_atomic_store(&flagA[sib], 1u, __ATOMIC_RELAXED, __HIP_MEMORY_SCOPE_AGENT);

    // ---- A loop: one GRU timestep per iteration, group-local sync ----
    for (int t = 0; t < TT; ++t) {
      // --- pre-barrier: x-part (depends on t only; overlaps sibling wait) ---
      const int rA = b0 + wv * 16 + col16;
      const float* paxf = x + ((size_t)rA * TT + t) * FDIM;
      const f32x4 zz = {0.f, 0.f, 0.f, 0.f};
      f32x4 acc[4] = {zz, zz, zz, zz};
      f32x4 accn[2] = {zz, zz};
      f32x4 acci[2] = {zz, zz};
      #pragma unroll
      for (int ks = 0; ks < 4; ++ks) {
        const int ko = ks * 32 + q8;
        const float4 u0 = *(const float4*)(paxf + ko);
        const float4 u1 = *(const float4*)(paxf + ko + 4);
        bf16x8 av;
        av[0]=(bf16_t)u0.x; av[1]=(bf16_t)u0.y; av[2]=(bf16_t)u0.z; av[3]=(bf16_t)u0.w;
        av[4]=(bf16_t)u1.x; av[5]=(bf16_t)u1.y; av[6]=(bf16_t)u1.z; av[7]=(bf16_t)u1.w;
        #pragma unroll
        for (int j = 0; j < 4; ++j) {
          const u32* pz = &L.a.rzf[(size_t)(j * 20 + ks) * 256 + lane];
          const u32x4 tz = {pz[0], pz[64], pz[128], pz[192]};
          acc[j] = mfma16(av, *(const bf16x8*)&tz, acc[j]);
        }
        #pragma unroll
        for (int j = 0; j < 2; ++j) {
          const u32* pn = &L.a.nif[(size_t)(j * 4 + ks) * 256 + lane];
          const u32x4 tn = {pn[0], pn[64], pn[128], pn[192]};
          acci[j] = mfma16(av, *(const bf16x8*)&tn, acci[j]);
        }
      }
      // --- barrier: siblings done t-1 AND B done t-2 (one parallel poll) ---
      if (wv == 0)
        wait_flags(flagA, (unsigned)(t + 1), flagB, (t >= 2) ? (unsigned)(t - 1) : 0u);
      __syncthreads();

      bf16_t* hr = hb + (size_t)((t + 1) & 1) * BB * HDIM;
      bf16_t* hw = hb + (size_t)(t & 1) * BB * HDIM;
      bf16_t* fw = ff + (size_t)(t & 1) * BB * HDIM;
      bf16_t* pah = hr + (size_t)rA * HDIM;
      // h part: 16 ks in QUADS (4 named pairs, 8 adjacent loads per group)
      #pragma unroll
      for (int kp = 0; kp < 4; ++kp) {
        const int ks0 = kp * 4, ks1 = kp * 4 + 1, ks2 = kp * 4 + 2, ks3 = kp * 4 + 3;
        const int ko0 = ks0 * 32 + q8, ko1 = ks1 * 32 + q8;
        const int ko2 = ks2 * 32 + q8, ko3 = ks3 * 32 + q8;
        u64 hqa[2];
        u64 hqb[2];
        u64 hqc[2];
        u64 hqd[2];
        hqa[0] = __hip_atomic_load((u64*)(pah + ko0),     __ATOMIC_RELAXED, __HIP_MEMORY_SCOPE_AGENT);
        hqa[1] = __hip_atomic_load((u64*)(pah + ko0) + 1, __ATOMIC_RELAXED, __HIP_MEMORY_SCOPE_AGENT);
        hqb[0] = __hip_atomic_load((u64*)(pah + ko1),     __ATOMIC_RELAXED, __HIP_MEMORY_SCOPE_AGENT);
        hqb[1] = __hip_atomic_load((u64*)(pah + ko1) + 1, __ATOMIC_RELAXED, __HIP_MEMORY_SCOPE_AGENT);
        hqc[0] = __hip_atomic_load((u64*)(pah + ko2),     __ATOMIC_RELAXED, __HIP_MEMORY_SCOPE_AGENT);
        hqc[1] = __hip_atomic_load((u64*)(pah + ko2) + 1, __ATOMIC_RELAXED, __HIP_MEMORY_SCOPE_AGENT);
        hqd[0] = __hip_atomic_load((u64*)(pah + ko3),     __ATOMIC_RELAXED, __HIP_MEMORY_SCOPE_AGENT);
        hqd[1] = __hip_atomic_load((u64*)(pah + ko3) + 1, __ATOMIC_RELAXED, __HIP_MEMORY_SCOPE_AGENT);
        const bf16x8 av0 = *(const bf16x8*)hqa;
        const bf16x8 av1 = *(const bf16x8*)hqb;
        const bf16x8 av2 = *(const bf16x8*)hqc;
        const bf16x8 av3 = *(const bf16x8*)hqd;
        #pragma unroll
        for (int j = 0; j < 4; ++j) {
          const u32* pz = &L.a.rzf[(size_t)(j * 20 + 4 + ks0) * 256 + lane];
          const u32x4 tz = {pz[0], pz[64], pz[128], pz[192]};
          acc[j] = mfma16(av0, *(const bf16x8*)&tz, acc[j]);
        }
        #pragma unroll
        for (int j = 0; j < 2; ++j) {
          const u32* pn = &L.a.nhf[(size_t)(j * 16 + ks0) * 256 + lane];
          const u32x4 tn = {pn[0], pn[64], pn[128], pn[192]};
          accn[j] = mfma16(av0, *(const bf16x8*)&tn, accn[j]);
        }
        #pragma unroll
        for (int j = 0; j < 4; ++j) {
          const u32* pz = &L.a.rzf[(size_t)(j * 20 + 4 + ks1) * 256 + lane];
          const u32x4 tz = {pz[0], pz[64], pz[128], pz[192]};
          acc[j] = mfma16(av1, *(const bf16x8*)&tz, acc[j]);
        }
        #pragma unroll
        for (int j = 0; j < 2; ++j) {
          const u32* pn = &L.a.nhf[(size_t)(j * 16 + ks1) * 256 + lane];
          const u32x4 tn = {pn[0], pn[64], pn[128], pn[192]};
          accn[j] = mfma16(av1, *(const bf16x8*)&tn, accn[j]);
        }
        #pragma unroll
        for (int j = 0; j < 4; ++j) {
          const u32* pz = &L.a.rzf[(size_t)(j * 20 + 4 + ks2) * 256 + lane];
          const u32x4 tz = {pz[0], pz[64], pz[128], pz[192]};
          acc[j] = mfma16(av2, *(const bf16x8*)&tz, acc[j]);
        }
        #pragma unroll
        for (int j = 0; j < 2; ++j) {
          const u32* pn = &L.a.nhf[(size_t)(j * 16 + ks2) * 256 + lane];
          const u32x4 tn = {pn[0], pn[64], pn[128], pn[192]};
          accn[j] = mfma16(av2, *(const bf16x8*)&tn, accn[j]);
        }
        #pragma unroll
        for (int j = 0; j < 4; ++j) {
          const u32* pz = &L.a.rzf[(size_t)(j * 20 + 4 + ks3) * 256 + lane];
          const u32x4 tz = {pz[0], pz[64], pz[128], pz[192]};
          acc[j] = mfma16(av3, *(const bf16x8*)&tz, acc[j]);
        }
        #pragma unroll
        for (int j = 0; j < 2; ++j) {
          const u32* pn = &L.a.nhf[(size_t)(j * 16 + ks3) * 256 + lane];
          const u32x4 tn = {pn[0], pn[64], pn[128], pn[192]};
          accn[j] = mfma16(av3, *(const bf16x8*)&tn, accn[j]);
        }
      }
      // dump gate sums to LDS exchange (C/D: col=lane&15, row=q*4+reg)
      #pragma unroll
      for (int j = 0; j < 4; ++j) {
        const int sl = j >> 1, cb = (j & 1) * 16 + col16;
        #pragma unroll
        for (int rg = 0; rg < 4; ++rg)
          L.a.ex[sl][wv * 16 + q * 4 + rg][cb] = acc[j][rg];
      }
      #pragma unroll
      for (int j = 0; j < 2; ++j) {
        const int cb = j * 16 + col16;
        #pragma unroll
        for (int rg = 0; rg < 4; ++rg) {
          L.a.ex[2][wv * 16 + q * 4 + rg][cb] = accn[j][rg];
          L.a.ex[3][wv * 16 + q * 4 + rg][cb] = acci[j][rg];
        }
      }
      __syncthreads();
      // elementwise GRU update: h_prev from LDS stash (no global RT)
      for (int e = tid; e < 512; e += NTHR) {
        const int row = e >> 3, cq = (e & 7) << 2;
        const int bidx = b0 + row;
        const u64 hp8 = L.a.hprev[row][cq >> 2];
        const bf16_t* hp4 = (const bf16_t*)&hp8;
        bf16_t hw4[4], fw4[4];
        const bool v = (t < seqA[row]);
        #pragma unroll
        for (int j = 0; j < 4; ++j) {
          const int c = cq + j;
          const float gr  = L.a.ex[0][row][c] + biasA[0][c];
          const float gz  = L.a.ex[1][row][c] + biasA[1][c];
          const float gnh = L.a.ex[2][row][c] + biasA[3][c];
          const float gni = L.a.ex[3][row][c] + biasA[2][c];
          const float r = sigm(gr), zg = sigm(gz);
          const float n = tanh_f(gni + r * gnh);
          const float hp = (float)hp4[j];
          const float hnew = (1.f - zg) * n + zg * hp;
          hw4[j] = (bf16_t)(v ? hnew : hp);
          fw4[j] = (bf16_t)(v ? hnew : 0.f);
        }
        L.a.hprev[row][cq >> 2] = *(u64*)hw4;
        __hip_atomic_store((u64*)(hw + (size_t)bidx * HDIM + c0 + cq), *(u64*)hw4,
                           __ATOMIC_RELAXED, __HIP_MEMORY_SCOPE_AGENT);
        __hip_atomic_store((u64*)(fw + (size_t)bidx * HDIM + c0 + cq), *(u64*)fw4,
                           __ATOMIC_RELAXED, __HIP_MEMORY_SCOPE_AGENT);
      }
      __syncthreads();                       // drain h/ff stores
      if (tid == 0)
        __hip_atomic_store(&flagA[sib], (unsigned)(t + 2), __ATOMIC_RELAXED, __HIP_MEMORY_SCOPE_AGENT);
    }
  } else {
    const int cidx = blk - 128;
    const int fc = cidx >> 3;      // 0..15 (sibling index)
    const int oc = fc & 3;         // out-col group for FF2 adds
    const int kq = fc >> 2;        // K-quarter (4 x 256)
    b0 = (cidx & 7) * 64;          // batch group (same XCD residue as A)
    f0 = fc * 64;                  // FF col group (16)
    const int o0 = oc * 16;
    for (int i = tid; i < 64 * 64; i += NTHR) {   // w1f: fi=j*16+ks
      const int ln = i & 63, fi = i >> 6;
      const int j = fi >> 4, ks = fi & 15;
      const int cc = ln & 15, qq = ln >> 4;
      const int fcol = f0 + j * 16 + cc;
      const int kb = ks * 32 + qq * 8;
      bf16_t tmp[8];
      for (int e = 0; e < 8; ++e) tmp[e] = (bf16_t)W1[(size_t)(kb + e) * FFD + fcol];
      const u32* t32 = (const u32*)tmp;
      u32* dst = &L.b.w1f[fi * 256 + ln];
      dst[0] = t32[0]; dst[64] = t32[1]; dst[128] = t32[2]; dst[192] = t32[3];
    }
    if (tid < 64) b1s[tid] = b1[f0 + tid];
    for (int i = tid; i < 8 * 64; i += NTHR) {    // w2f: own K-quarter, fi=ks<8
      const int ln = i & 63, ks = i >> 6;
      const int cc = ln & 15, qq = ln >> 4;
      const int kb = kq * 256 + ks * 32 + qq * 8;
      bf16_t tmp[8];
      for (int e = 0; e < 8; ++e) tmp[e] = (bf16_t)W2[(kb + e) * OUTD + o0 + cc];
      const u32* t32 = (const u32*)tmp;
      u32* dst = &L.b.w2f[ks * 256 + ln];
      dst[0] = t32[0]; dst[64] = t32[1]; dst[128] = t32[2]; dst[192] = t32[3];
    }
    // R23: ALL B blocks stage b2 (full 64) + seqC; finalize is split evenly.
    if (tid < 64) b2s[tid] = b2[tid];
    if (tid < 64) seqC[tid] = seq[b0 + tid];
    __syncthreads();               // LDS staging visible block-wide

    // R23 finalize slice: this block owns 256 of the group's 4096 elems,
    // 1 elem/thread: base = fc*256+tid -> (ocF, rowF, colF).
    const int baseF = fc * 256 + tid;
    const int ocF = baseF >> 10, remF = baseF & 1023;
    const int rowF = remF >> 4, colF = remF & 15;

    // ---- B loop: iter u = FF1(t=u), FF2-chunk adds(t=u-1), finalize(t=u-2)
    float* pg = psc + (size_t)grp * PGRP + (size_t)oc * (64 * 16);
    float* pgf = psc + (size_t)grp * PGRP + (size_t)ocF * (64 * 16) + rowF * 16 + colF;
    for (int u = 0; u <= TT + 1; ++u) {
      if (wv == 0)
        wait_flags(flagB, (unsigned)u, flagA, (u < TT) ? (unsigned)(u + 2) : 0u);
      __syncthreads();

      // --- hoisted issue: FF2 fragment loads (t=u-1; inputs ready at head)
      const int rCF = b0 + wv * 16 + col16;
      bf16_t* paF = hd + (size_t)((u - 1) & 1) * BB * FFD + (size_t)rCF * FFD + kq * 256 + q8;
      u64 fz0a = 0, fz0b = 0, fz1a = 0, fz1b = 0, fz2a = 0, fz2b = 0, fz3a = 0, fz3b = 0;
      u64 fz4a = 0, fz4b = 0, fz5a = 0, fz5b = 0, fz6a = 0, fz6b = 0, fz7a = 0, fz7b = 0;
      if (u >= 1 && u <= TT) {
        fz0a = __hip_atomic_load((u64*)(paF + 0 * 32),     __ATOMIC_RELAXED, __HIP_MEMORY_SCOPE_AGENT);
        fz0b = __hip_atomic_load((u64*)(paF + 0 * 32) + 1, __ATOMIC_RELAXED, __HIP_MEMORY_SCOPE_AGENT);
        fz1a = __hip_atomic_load((u64*)(paF + 1 * 32),     __ATOMIC_RELAXED, __HIP_MEMORY_SCOPE_AGENT);
        fz1b = __hip_atomic_load((u64*)(paF + 1 * 32) + 1, __ATOMIC_RELAXED, __HIP_MEMORY_SCOPE_AGENT);
        fz2a = __hip_atomic_load((u64*)(paF + 2 * 32),     __ATOMIC_RELAXED, __HIP_MEMORY_SCOPE_AGENT);
        fz2b = __hip_atomic_load((u64*)(paF + 2 * 32) + 1, __ATOMIC_RELAXED, __HIP_MEMORY_SCOPE_AGENT);
        fz3a = __hip_atomic_load((u64*)(paF + 3 * 32),     __ATOMIC_RELAXED, __HIP_MEMORY_SCOPE_AGENT);
        fz3b = __hip_atomic_load((u64*)(paF + 3 * 32) + 1, __ATOMIC_RELAXED, __HIP_MEMORY_SCOPE_AGENT);
        fz4a = __hip_atomic_load((u64*)(paF + 4 * 32),     __ATOMIC_RELAXED, __HIP_MEMORY_SCOPE_AGENT);
        fz4b = __hip_atomic_load((u64*)(paF + 4 * 32) + 1, __ATOMIC_RELAXED, __HIP_MEMORY_SCOPE_AGENT);
        fz5a = __hip_atomic_load((u64*)(paF + 5 * 32),     __ATOMIC_RELAXED, __HIP_MEMORY_SCOPE_AGENT);
        fz5b = __hip_atomic_load((u64*)(paF + 5 * 32) + 1, __ATOMIC_RELAXED, __HIP_MEMORY_SCOPE_AGENT);
        fz6a = __hip_atomic_load((u64*)(paF + 6 * 32),     __ATOMIC_RELAXED, __HIP_MEMORY_SCOPE_AGENT);
        fz6b = __hip_atomic_load((u64*)(paF + 6 * 32) + 1, __ATOMIC_RELAXED, __HIP_MEMORY_SCOPE_AGENT);
        fz7a = __hip_atomic_load((u64*)(paF + 7 * 32),     __ATOMIC_RELAXED, __HIP_MEMORY_SCOPE_AGENT);
        fz7b = __hip_atomic_load((u64*)(paF + 7 * 32) + 1, __ATOMIC_RELAXED, __HIP_MEMORY_SCOPE_AGENT);
      }
      // --- hoisted issue: finalize pscr load (t2=u-2; 1 f32/thread)
      float* ppF = pgf + (size_t)((u - 2) & 1) * PSLOT;
      u32 fpv = 0;
      if (u >= 2) {
        fpv = __hip_atomic_load((u32*)ppF, __ATOMIC_RELAXED, __HIP_MEMORY_SCOPE_AGENT);
      }

      if (u < TT) {                        // FF1 for t = u; 16 ks in 4 quads
        const int t = u;
        bf16_t* fr = ff + (size_t)(t & 1) * BB * HDIM;
        bf16_t* hwid = hd + (size_t)(t & 1) * BB * FFD;
        const int rB = b0 + wv * 16 + col16;
        bf16_t* pa = fr + (size_t)rB * HDIM;
        const f32x4 zz = {0.f, 0.f, 0.f, 0.f};
        f32x4 acc[4] = {zz, zz, zz, zz};
        #pragma unroll
        for (int kp = 0; kp < 4; ++kp) {
          const int ks0 = kp * 4, ks1 = kp * 4 + 1, ks2 = kp * 4 + 2, ks3 = kp * 4 + 3;
          const int ko0 = ks0 * 32 + q8, ko1 = ks1 * 32 + q8;
          const int ko2 = ks2 * 32 + q8, ko3 = ks3 * 32 + q8;
          u64 fqa[2];
          u64 fqb[2];
          u64 fqc[2];
          u64 fqd[2];
          fqa[0] = __hip_atomic_load((u64*)(pa + ko0),     __ATOMIC_RELAXED, __HIP_MEMORY_SCOPE_AGENT);
          fqa[1] = __hip_atomic_load((u64*)(pa + ko0) + 1, __ATOMIC_RELAXED, __HIP_MEMORY_SCOPE_AGENT);
          fqb[0] = __hip_atomic_load((u64*)(pa + ko1),     __ATOMIC_RELAXED, __HIP_MEMORY_SCOPE_AGENT);
          fqb[1] = __hip_atomic_load((u64*)(pa + ko1) + 1, __ATOMIC_RELAXED, __HIP_MEMORY_SCOPE_AGENT);
          fqc[0] = __hip_atomic_load((u64*)(pa + ko2),     __ATOMIC_RELAXED, __HIP_MEMORY_SCOPE_AGENT);
          fqc[1] = __hip_atomic_load((u64*)(pa + ko2) + 1, __ATOMIC_RELAXED, __HIP_MEMORY_SCOPE_AGENT);
          fqd[0] = __hip_atomic_load((u64*)(pa + ko3),     __ATOMIC_RELAXED, __HIP_MEMORY_SCOPE_AGENT);
          fqd[1] = __hip_atomic_load((u64*)(pa + ko3) + 1, __ATOMIC_RELAXED, __HIP_MEMORY_SCOPE_AGENT);
          const bf16x8 av0 = *(const bf16x8*)fqa;
          const bf16x8 av1 = *(const bf16x8*)fqb;
          const bf16x8 av2 = *(const bf16x8*)fqc;
          const bf16x8 av3 = *(const bf16x8*)fqd;
          #pragma unroll
          for (int j = 0; j < 4; ++j) {
            const u32* pw = &L.b.w1f[(size_t)(j * 16 + ks0) * 256 + lane];
            const u32x4 tw = {pw[0], pw[64], pw[128], pw[192]};
            acc[j] = mfma16(av0, *(const bf16x8*)&tw, acc[j]);
          }
          #pragma unroll
          for (int j = 0; j < 4; ++j) {
            const u32* pw = &L.b.w1f[(size_t)(j * 16 + ks1) * 256 + lane];
            const u32x4 tw = {pw[0], pw[64], pw[128], pw[192]};
            acc[j] = mfma16(av1, *(const bf16x8*)&tw, acc[j]);
          }
          #pragma unroll
          for (int j = 0; j < 4; ++j) {
            const u32* pw = &L.b.w1f[(size_t)(j * 16 + ks2) * 256 + lane];
            const u32x4 tw = {pw[0], pw[64], pw[128], pw[192]};
            acc[j] = mfma16(av2, *(const bf16x8*)&tw, acc[j]);
          }
          #pragma unroll
          for (int j = 0; j < 4; ++j) {
            const u32* pw = &L.b.w1f[(size_t)(j * 16 + ks3) * 256 + lane];
            const u32x4 tw = {pw[0], pw[64], pw[128], pw[192]};
            acc[j] = mfma16(av3, *(const bf16x8*)&tw, acc[j]);
          }
        }
        // relu + bias -> LDS restage -> contiguous 8B coherent stores
        #pragma unroll
        for (int j = 0; j < 4; ++j) {
          const int fcc = j * 16 + col16;
          #pragma unroll
          for (int rg = 0; rg < 4; ++rg)
            L.b.st[(wv * 16 + q * 4 + rg) * 72 + fcc] =
                (bf16_t)fmaxf(acc[j][rg] + b1s[fcc], 0.f);
        }
        __syncthreads();
        for (int w = tid; w < 1024; w += NTHR) {
          const int r = w >> 4, cq = (w & 15) * 4;
          const u64 pk = *(const u64*)&L.b.st[r * 72 + cq];
          __hip_atomic_store((u64*)(hwid + (size_t)(b0 + r) * FFD + f0 + cq), pk,
                             __ATOMIC_RELAXED, __HIP_MEMORY_SCOPE_AGENT);
        }
      }
      if (u >= 1 && u <= TT) {             // FF2 consume (loads landed)
        const int t = u - 1;
        f32x4 acc = {0.f, 0.f, 0.f, 0.f};
        {
          u64 w0[2] = {fz0a, fz0b};
          const u32* pw = &L.b.w2f[(size_t)0 * 256 + lane];
          const u32x4 tw = {pw[0], pw[64], pw[128], pw[192]};
          acc = mfma16(*(const bf16x8*)w0, *(const bf16x8*)&tw, acc);
        }
        {
          u64 w1v[2] = {fz1a, fz1b};
          const u32* pw = &L.b.w2f[(size_t)1 * 256 + lane];
          const u32x4 tw = {pw[0], pw[64], pw[128], pw[192]};
          acc = mfma16(*(const bf16x8*)w1v, *(const bf16x8*)&tw, acc);
        }
        {
          u64 w2v[2] = {fz2a, fz2b};
          const u32* pw = &L.b.w2f[(size_t)2 * 256 + lane];
          const u32x4 tw = {pw[0], pw[64], pw[128], pw[192]};
          acc = mfma16(*(const bf16x8*)w2v, *(const bf16x8*)&tw, acc);
        }
        {
          u64 w3v[2] = {fz3a, fz3b};
          const u32* pw = &L.b.w2f[(size_t)3 * 256 + lane];
          const u32x4 tw = {pw[0], pw[64], pw[128], pw[192]};
          acc = mfma16(*(const bf16x8*)w3v, *(const bf16x8*)&tw, acc);
        }
        {
          u64 w4v[2] = {fz4a, fz4b};
          const u32* pw = &L.b.w2f[(size_t)4 * 256 + lane];
          const u32x4 tw = {pw[0], pw[64], pw[128], pw[192]};
          acc = mfma16(*(const bf16x8*)w4v, *(const bf16x8*)&tw, acc);
        }
        {
          u64 w5v[2] = {fz5a, fz5b};
          const u32* pw = &L.b.w2f[(size_t)5 * 256 + lane];
          const u32x4 tw = {pw[0], pw[64], pw[128], pw[192]};
          acc = mfma16(*(const bf16x8*)w5v, *(const bf16x8*)&tw, acc);
        }
        {
          u64 w6v[2] = {fz6a, fz6b};
          const u32* pw = &L.b.w2f[(size_t)6 * 256 + lane];
          const u32x4 tw = {pw[0], pw[64], pw[128], pw[192]};
          acc = mfma16(*(const bf16x8*)w6v, *(const bf16x8*)&tw, acc);
        }
        {
          u64 w7v[2] = {fz7a, fz7b};
          const u32* pw = &L.b.w2f[(size_t)7 * 256 + lane];
          const u32x4 tw = {pw[0], pw[64], pw[128], pw[192]};
          acc = mfma16(*(const bf16x8*)w7v, *(const bf16x8*)&tw, acc);
        }
        float* pb = pg + (size_t)(t & 1) * PSLOT;
        #pragma unroll
        for (int rg = 0; rg < 4; ++rg)
          atomicAdd(pb + (wv * 16 + q * 4 + rg) * 16 + col16, acc[rg]);
      }
      if (u >= 2) {                        // finalize slice: 1 elem/thread
        const int t2 = u - 2;
        float pv;
        *(u32*)&pv = fpv;
        const bool v = (t2 < seqC[rowF]);
        out[((size_t)(b0 + rowF) * TT + t2) * OUTD + ocF * 16 + colF] =
            v ? (pv + b2s[ocF * 16 + colF]) : PADV;
        // re-zero the slot for t = u (replay-safe, gated by flagB >= u+1)
        __hip_atomic_store((u32*)ppF, 0u, __ATOMIC_RELAXED, __HIP_MEMORY_SCOPE_AGENT);
      }
      __syncthreads();                     // drain hd stores / adds / zeros
      if (tid == 0)
        __hip_atomic_store(&flagB[fc], (unsigned)(u + 1), __ATOMIC_RELAXED, __HIP_MEMORY_SCOPE_AGENT);
    }
  }
}

extern "C" void kernel_launch(void* const* d_in, const int* in_sizes, int n_in,
                              void* d_out, int out_size, void* d_ws, size_t ws_size,
                              hipStream_t stream) {
  const float* x   = (const float*)d_in[0];
  const int*   seq = (const int*)d_in[1];
  const float* Wih = (const float*)d_in[2];
  const float* Whh = (const float*)d_in[3];
  const float* bih = (const float*)d_in[4];
  const float* bhh = (const float*)d_in[5];
  const float* W1  = (const float*)d_in[6];
  const float* b1  = (const float*)d_in[7];
  const float* W2  = (const float*)d_in[8];
  const float* b2  = (const float*)d_in[9];
  float* out = (float*)d_out;
  char* ws = (char*)d_ws;

  unsigned* bar = (unsigned*)ws;                       // flag lines, 128B apart
  float* psc = (float*)(ws + 4096);                    // 2*PSLOT f32 = 256KB
  bf16_t* hb = (bf16_t*)(ws + 4096 + 2 * PSLOT * 4);   // h ping-pong  2*B*H
  bf16_t* ff = hb + (size_t)2 * BB * HDIM;             // ffin ping-pong
  bf16_t* hd = ff + (size_t)2 * BB * HDIM;             // hid ping-pong 2*B*FF
  // total scratch ~4.5 MB

  hipMemsetAsync(ws, 0, 4096 + 2 * PSLOT * 4, stream);
  void* args[] = {&x, &seq, &Wih, &Whh, &bih, &bhh, &W1, &b1, &W2, &b2,
                  &out, &hb, &ff, &hd, &psc, &bar};
  hipLaunchCooperativeKernel((void*)gru_net_kernel, dim3(NBLK), dim3(NTHR),
                             args, 0, stream);
}